// Round 1
// baseline (3380.204 us; speedup 1.0000x reference)
//
#include <hip/hip_runtime.h>
#include <math.h>

#define N_NODES 10000
#define NT_     157                 // ceil(10000/64)
#define NPAD    (NT_*64)            // 10048
#define E_      320000

// ---- workspace layout (float offsets) ----
#define O_DINV1 0
#define O_DINV2 10000
#define O_SMALL 20000
#define S_CSUM1 (O_SMALL+0)
#define S_CSUM2 (O_SMALL+32)
#define S_GC1   (O_SMALL+64)
#define S_GC2   (O_SMALL+96)
#define S_P1    (O_SMALL+128)
#define S_P2    (O_SMALL+160)
#define S_S1ACC (O_SMALL+192)
#define S_S2ACC (O_SMALL+208)
#define S_S0    (O_SMALL+224)
#define S_B     (O_SMALL+240)     // 512
#define S_C     (O_SMALL+752)     // 16
#define S_HIST  (O_SMALL+768)     // 64*16 uints
#define ZERO_N  (O_SMALL+1792)    // zero range [0, 21792)
#define O_MINMAX 21800            // 2 uints, init separately
#define O_INV1  21808
#define O_INV2  31808
#define O_BUFH  41808             // N*128
#define O_BUFO  (O_BUFH + N_NODES*128)
#define O_AF1   (O_BUFO + N_NODES*128)  // NPAD*32
#define O_AF2   (O_AF1 + NPAD*32)

__device__ __forceinline__ unsigned f2ord(float f){
  unsigned u = __float_as_uint(f);
  return (u & 0x80000000u) ? ~u : (u | 0x80000000u);
}
__device__ __forceinline__ float ord2f(unsigned u){
  return (u & 0x80000000u) ? __uint_as_float(u & 0x7FFFFFFFu) : __uint_as_float(~u);
}

__global__ void init_k(float* ws){
  int i = blockIdx.x*blockDim.x + threadIdx.x;
  for(; i<ZERO_N; i += gridDim.x*blockDim.x) ws[i] = 0.f;
  if(blockIdx.x==0 && threadIdx.x==0){
    unsigned* mm = (unsigned*)(ws + O_MINMAX);
    mm[0] = 0xFFFFFFFFu;  // encoded +inf-ish for min
    mm[1] = 0u;           // encoded -inf-ish for max
  }
}

__global__ void deg_k(const int* __restrict__ dst, float* __restrict__ degc, int E){
  int i = blockIdx.x*blockDim.x + threadIdx.x;
  if(i < E) atomicAdd(&degc[dst[i]], 1.0f);
}

__global__ void degfin_k(float* __restrict__ dinv, float* __restrict__ inv, int n){
  int i = blockIdx.x*blockDim.x + threadIdx.x;
  if(i < n){
    float d = dinv[i] + 1.0f;
    dinv[i] = 1.0f/sqrtf(d);
    inv[i]  = 1.0f/d;
  }
}

// C[n,FOUT] = act(A[n,FIN]) @ W[FIN,FOUT]
template<int FIN, int FOUT, bool RELU>
__global__ __launch_bounds__(256) void gemm_k(const float* __restrict__ A,
                                              const float* __restrict__ W,
                                              float* __restrict__ C, int n){
  constexpr int KC = (FIN > 64) ? 64 : FIN;
  __shared__ float Ws[KC*FOUT];
  constexpr int ROWS = 256/FOUT;
  int row = blockIdx.x*ROWS + (int)threadIdx.x/FOUT;
  int col = threadIdx.x % FOUT;
  float acc = 0.f;
  for(int kc=0; kc<FIN; kc+=KC){
    __syncthreads();
    for(int t=threadIdx.x; t<KC*FOUT; t+=256) Ws[t] = W[kc*FOUT + t];
    __syncthreads();
    if(row < n){
      const float* a = A + (size_t)row*FIN + kc;
      #pragma unroll
      for(int k=0;k<KC;k++){
        float v = a[k];
        if(RELU) v = fmaxf(v, 0.f);
        acc += v*Ws[k*FOUT+col];
      }
    }
  }
  if(row < n) C[(size_t)row*FOUT+col] = acc;
}

// out[n,f] = h[n,f]*inv[n] + b[f]
template<int F>
__global__ void self_k(const float* __restrict__ h, const float* __restrict__ inv,
                       const float* __restrict__ b, float* __restrict__ out, int n){
  int i = blockIdx.x*blockDim.x + threadIdx.x;
  if(i < n*F){
    int node = i/F, f = i%F;
    out[i] = h[i]*inv[node] + b[f];
  }
}

// out[dst] += dinv[src]*dinv[dst] * h[src]
template<int F>
__global__ void scat_k(const float* __restrict__ h, const int* __restrict__ src,
                       const int* __restrict__ dst, const float* __restrict__ dinv,
                       float* __restrict__ out, int E){
  constexpr int F4 = F/4;
  int i = blockIdx.x*blockDim.x + threadIdx.x;
  if(i >= E*F4) return;
  int e = i/F4, c = (i%F4)*4;
  int s = src[e], d = dst[e];
  float coef = dinv[s]*dinv[d];
  float4 hv = *(const float4*)(h + (size_t)s*F + c);
  float* op = out + (size_t)d*F + c;
  atomicAdd(op+0, coef*hv.x); atomicAdd(op+1, coef*hv.y);
  atomicAdd(op+2, coef*hv.z); atomicAdd(op+3, coef*hv.w);
}

// similarity tiles: pass A = min/max, pass B = histogram
template<bool HIST>
__global__ __launch_bounds__(256) void sim_k(const float* __restrict__ af1,
                                             const float* __restrict__ af2,
                                             unsigned* __restrict__ minmax,
                                             unsigned* __restrict__ ghist){
  __shared__ float ta[32*64], tb[32*64];   // k-major tiles
  __shared__ float red[256];
  __shared__ unsigned lh[64*17];
  int bx = blockIdx.x % NT_, by = blockIdx.x / NT_;
  int i0 = by*64, j0 = bx*64;
  for(int t=threadIdx.x; t<512; t+=256){
    int row = t>>3, c4 = (t&7)*4;
    float4 va = *(const float4*)(af1 + (size_t)(i0+row)*32 + c4);
    ta[(c4+0)*64+row]=va.x; ta[(c4+1)*64+row]=va.y; ta[(c4+2)*64+row]=va.z; ta[(c4+3)*64+row]=va.w;
    float4 vb = *(const float4*)(af2 + (size_t)(j0+row)*32 + c4);
    tb[(c4+0)*64+row]=vb.x; tb[(c4+1)*64+row]=vb.y; tb[(c4+2)*64+row]=vb.z; tb[(c4+3)*64+row]=vb.w;
  }
  if(HIST){ for(int t=threadIdx.x; t<64*17; t+=256) lh[t]=0u; }
  __syncthreads();
  int tx = threadIdx.x & 15, ty = threadIdx.x >> 4;
  int ra = ty*4, rb = tx*4;
  float acc[4][4];
  #pragma unroll
  for(int r=0;r<4;r++){
    #pragma unroll
    for(int c=0;c<4;c++) acc[r][c]=0.f;
  }
  #pragma unroll 4
  for(int k=0;k<32;k++){
    float4 av = *(const float4*)&ta[k*64+ra];
    float4 bv = *(const float4*)&tb[k*64+rb];
    float a4[4]={av.x,av.y,av.z,av.w};
    float b4[4]={bv.x,bv.y,bv.z,bv.w};
    #pragma unroll
    for(int r=0;r<4;r++){
      #pragma unroll
      for(int c=0;c<4;c++) acc[r][c] += a4[r]*b4[c];
    }
  }
  if(!HIST){
    float m = INFINITY, M = -INFINITY;
    #pragma unroll
    for(int r=0;r<4;r++){
      if(i0+ra+r >= N_NODES) continue;
      #pragma unroll
      for(int c=0;c<4;c++){
        if(j0+rb+c >= N_NODES) continue;
        float v = acc[r][c];
        m = fminf(m, v); M = fmaxf(M, v);
      }
    }
    red[threadIdx.x]=m; __syncthreads();
    for(int s=128;s;s>>=1){ if(threadIdx.x<s) red[threadIdx.x]=fminf(red[threadIdx.x],red[threadIdx.x+s]); __syncthreads(); }
    if(threadIdx.x==0) atomicMin(&minmax[0], f2ord(red[0]));
    __syncthreads();
    red[threadIdx.x]=M; __syncthreads();
    for(int s=128;s;s>>=1){ if(threadIdx.x<s) red[threadIdx.x]=fmaxf(red[threadIdx.x],red[threadIdx.x+s]); __syncthreads(); }
    if(threadIdx.x==0) atomicMax(&minmax[1], f2ord(red[0]));
  } else {
    float lo = ord2f(minmax[0]);
    float hi = ord2f(minmax[1]);
    float denom = (hi-lo) + 1e-12f;
    unsigned base = (threadIdx.x & 63)*17;
    #pragma unroll
    for(int r=0;r<4;r++){
      if(i0+ra+r >= N_NODES) continue;
      #pragma unroll
      for(int c=0;c<4;c++){
        if(j0+rb+c >= N_NODES) continue;
        int idx = (int)((acc[r][c]-lo)/denom*16.0f);   // match reference op order
        idx = idx<0 ? 0 : (idx>15 ? 15 : idx);
        atomicAdd(&lh[base+idx], 1u);
      }
    }
    __syncthreads();
    if(threadIdx.x<16){
      unsigned s=0;
      for(int c2=0;c2<64;c2++) s += lh[c2*17+threadIdx.x];
      atomicAdd(&ghist[(blockIdx.x & 63)*16 + threadIdx.x], s);
    }
  }
}

__global__ void colsum_k(const float* __restrict__ af, float* __restrict__ csum, int n){
  int f = threadIdx.x % 32;
  int rg = threadIdx.x / 32;  // 0..7
  float acc = 0.f;
  for(int node = blockIdx.x*8 + rg; node < n; node += gridDim.x*8)
    acc += af[(size_t)node*32 + f];
  __shared__ float s[256];
  s[threadIdx.x]=acc; __syncthreads();
  if(threadIdx.x<32){
    float v=0.f;
    for(int r=0;r<8;r++) v += s[r*32+threadIdx.x];
    atomicAdd(&csum[threadIdx.x], v);
  }
}

__global__ void gc_k(const float* __restrict__ csum, const float* __restrict__ att_w,
                     float* __restrict__ gc){
  int j = threadIdx.x;
  if(j < 32){
    float acc = 0.f;
    for(int f=0;f<32;f++) acc += csum[f]*att_w[f*32+j];
    gc[j] = tanhf(acc * (1.0f/N_NODES));
  }
}

__global__ __launch_bounds__(256) void attpool_k(const float* __restrict__ af,
                                                 const float* __restrict__ gc,
                                                 float* __restrict__ p, int n){
  __shared__ float sgc[32];
  if(threadIdx.x<32) sgc[threadIdx.x]=gc[threadIdx.x];
  __syncthreads();
  float pacc[32];
  #pragma unroll
  for(int f=0;f<32;f++) pacc[f]=0.f;
  for(int node = blockIdx.x*blockDim.x + threadIdx.x; node < n; node += gridDim.x*blockDim.x){
    const float* row = af + (size_t)node*32;
    float d = 0.f;
    #pragma unroll
    for(int f=0;f<32;f++) d += row[f]*sgc[f];
    float sig = 1.0f/(1.0f+expf(-d));
    #pragma unroll
    for(int f=0;f<32;f++) pacc[f] += row[f]*sig;
  }
  #pragma unroll
  for(int f=0;f<32;f++){
    float v = pacc[f];
    for(int off=32; off; off>>=1) v += __shfl_down(v, off, 64);
    if((threadIdx.x & 63)==0) atomicAdd(&p[f], v);
  }
}

__global__ void s0_k(const float* __restrict__ p1, const float* __restrict__ p2,
                     const float* __restrict__ tn_w, const float* __restrict__ tn_wb,
                     const float* __restrict__ tn_bias, float* __restrict__ s0out){
  int k = threadIdx.x;
  if(k < 16){
    float s = 0.f;
    for(int f1=0;f1<32;f1++){
      float a = p1[f1];
      for(int f2=0;f2<32;f2++) s += a*tn_w[(f1*32+f2)*16+k]*p2[f2];
    }
    float blk = 0.f;
    for(int f=0;f<32;f++) blk += tn_wb[k*64+f]*p1[f] + tn_wb[k*64+32+f]*p2[f];
    s0out[k] = fmaxf(s + blk + tn_bias[k], 0.f);
  }
}

// B[g,k] = sum_f tn_w[g,f,k]*pv[f] + tn_wb[k,g];  c[k] = sum_f tn_wb[k,32+f]*pv[f] + bias[k]
__global__ void bbuild_k(const float* __restrict__ pv, const float* __restrict__ tn_w,
                         const float* __restrict__ tn_wb, const float* __restrict__ tn_bias,
                         float* __restrict__ B, float* __restrict__ c){
  int t = threadIdx.x;
  if(t < 512){
    int g = t/16, k = t%16;
    float acc = 0.f;
    for(int f=0;f<32;f++) acc += tn_w[(g*32+f)*16+k]*pv[f];
    B[t] = acc + tn_wb[k*64+g];
  }
  if(t < 16){
    float acc = 0.f;
    for(int f=0;f<32;f++) acc += tn_wb[t*64+32+f]*pv[f];
    c[t] = acc + tn_bias[t];
  }
}

__global__ __launch_bounds__(256) void tnmean_k(const float* __restrict__ X,
                                                const float* __restrict__ B,
                                                const float* __restrict__ c,
                                                float* __restrict__ acc, int n){
  __shared__ float sB[512];
  __shared__ float sc[16];
  for(int i=threadIdx.x;i<512;i+=256) sB[i]=B[i];
  if(threadIdx.x<16) sc[threadIdx.x]=c[threadIdx.x];
  __syncthreads();
  float a[16];
  #pragma unroll
  for(int k=0;k<16;k++) a[k]=0.f;
  for(int node = blockIdx.x*blockDim.x + threadIdx.x; node < n; node += gridDim.x*blockDim.x){
    const float* row = X + (size_t)node*32;
    float rv[32];
    #pragma unroll
    for(int g=0;g<32;g++) rv[g]=row[g];
    #pragma unroll
    for(int k=0;k<16;k++){
      float y = sc[k];
      #pragma unroll
      for(int g=0;g<32;g++) y += rv[g]*sB[g*16+k];
      a[k] += fmaxf(y, 0.f);
    }
  }
  #pragma unroll
  for(int k=0;k<16;k++){
    float v = a[k];
    for(int off=32; off; off>>=1) v += __shfl_down(v, off, 64);
    if((threadIdx.x & 63)==0) atomicAdd(&acc[k], v);
  }
}

__global__ void final_k(const float* __restrict__ ws, const unsigned* __restrict__ ghist,
                        const float* __restrict__ fc1_w, const float* __restrict__ fc1_b,
                        const float* __restrict__ fc2_w, const float* __restrict__ fc2_b,
                        float* __restrict__ out){
  if(threadIdx.x != 0 || blockIdx.x != 0) return;
  float scores[64];
  const float invN = 1.0f/N_NODES;
  for(int k=0;k<16;k++) scores[k]      = ws[S_S0+k];
  for(int k=0;k<16;k++) scores[16+k]   = ws[S_S1ACC+k]*invN;
  for(int k=0;k<16;k++) scores[32+k]   = ws[S_S2ACC+k]*invN;
  float tot = 0.f, hv[16];
  for(int b=0;b<16;b++){
    unsigned cnt = 0;
    for(int c=0;c<64;c++) cnt += ghist[c*16+b];
    float v = (float)cnt;
    // emulate fp32 +1.0 accumulation saturation at 2^24 (reference scatter-add)
    if(v > 16777216.0f) v = 16777216.0f;
    hv[b]=v; tot+=v;
  }
  for(int b=0;b<16;b++) scores[48+b] = hv[b]/tot;
  float h[16];
  for(int j=0;j<16;j++){
    float a = fc1_b[j];
    for(int i=0;i<64;i++) a += scores[i]*fc1_w[i*16+j];
    h[j] = fmaxf(a, 0.f);
  }
  float o = fc2_b[0];
  for(int j=0;j<16;j++) o += h[j]*fc2_w[j];
  out[0] = 1.0f/(1.0f+expf(-o));
}

extern "C" void kernel_launch(void* const* d_in, const int* in_sizes, int n_in,
                              void* d_out, int out_size, void* d_ws, size_t ws_size,
                              hipStream_t stream){
  const float* x1      = (const float*)d_in[0];
  const float* x2      = (const float*)d_in[1];
  const int*   ei1     = (const int*)d_in[2];
  const int*   ei2     = (const int*)d_in[3];
  const float* W1      = (const float*)d_in[4];
  const float* b1      = (const float*)d_in[5];
  const float* W2      = (const float*)d_in[6];
  const float* b2      = (const float*)d_in[7];
  const float* W3      = (const float*)d_in[8];
  const float* b3      = (const float*)d_in[9];
  const float* att_w   = (const float*)d_in[10];
  const float* tn_w    = (const float*)d_in[11];
  const float* tn_wb   = (const float*)d_in[12];
  const float* tn_bias = (const float*)d_in[13];
  const float* fc1_w   = (const float*)d_in[14];
  const float* fc1_b   = (const float*)d_in[15];
  const float* fc2_w   = (const float*)d_in[16];
  const float* fc2_b   = (const float*)d_in[17];

  float* ws = (float*)d_ws;
  float* out = (float*)d_out;
  const int N = N_NODES, E = E_;

  unsigned* minmax = (unsigned*)(ws + O_MINMAX);
  unsigned* ghist  = (unsigned*)(ws + S_HIST);

  init_k<<<86, 256, 0, stream>>>(ws);

  // degrees for both graphs
  deg_k<<<(E+255)/256, 256, 0, stream>>>(ei1 + E, ws + O_DINV1, E);
  deg_k<<<(E+255)/256, 256, 0, stream>>>(ei2 + E, ws + O_DINV2, E);
  degfin_k<<<(N+255)/256, 256, 0, stream>>>(ws + O_DINV1, ws + O_INV1, N);
  degfin_k<<<(N+255)/256, 256, 0, stream>>>(ws + O_DINV2, ws + O_INV2, N);

  for(int g=0; g<2; g++){
    const float* x   = g ? x2 : x1;
    const int* src   = (g ? ei2 : ei1);
    const int* dst   = src + E;
    float* dinv      = ws + (g ? O_DINV2 : O_DINV1);
    float* inv       = ws + (g ? O_INV2  : O_INV1);
    float* af        = ws + (g ? O_AF2   : O_AF1);
    float* bufH      = ws + O_BUFH;
    float* bufO      = ws + O_BUFO;

    // layer 1: 128 -> 128
    gemm_k<128,128,false><<<N/2, 256, 0, stream>>>(x, W1, bufH, N);
    self_k<128><<<(N*128+255)/256, 256, 0, stream>>>(bufH, inv, b1, bufO, N);
    scat_k<128><<<(E*32+255)/256, 256, 0, stream>>>(bufH, src, dst, dinv, bufO, E);
    // layer 2: 128 -> 64 (relu on input)
    gemm_k<128,64,true><<<N/4, 256, 0, stream>>>(bufO, W2, bufH, N);
    self_k<64><<<(N*64+255)/256, 256, 0, stream>>>(bufH, inv, b2, bufO, N);
    scat_k<64><<<(E*16+255)/256, 256, 0, stream>>>(bufH, src, dst, dinv, bufO, E);
    // layer 3: 64 -> 32 (relu on input), output -> af
    gemm_k<64,32,true><<<N/8, 256, 0, stream>>>(bufO, W3, bufH, N);
    self_k<32><<<(N*32+255)/256, 256, 0, stream>>>(bufH, inv, b3, af, N);
    scat_k<32><<<(E*8+255)/256, 256, 0, stream>>>(bufH, src, dst, dinv, af, E);
  }

  // similarity: min/max pass then histogram pass
  sim_k<false><<<NT_*NT_, 256, 0, stream>>>(ws+O_AF1, ws+O_AF2, minmax, ghist);
  sim_k<true ><<<NT_*NT_, 256, 0, stream>>>(ws+O_AF1, ws+O_AF2, minmax, ghist);

  // attention pooling
  colsum_k<<<64, 256, 0, stream>>>(ws+O_AF1, ws+S_CSUM1, N);
  colsum_k<<<64, 256, 0, stream>>>(ws+O_AF2, ws+S_CSUM2, N);
  gc_k<<<1, 64, 0, stream>>>(ws+S_CSUM1, att_w, ws+S_GC1);
  gc_k<<<1, 64, 0, stream>>>(ws+S_CSUM2, att_w, ws+S_GC2);
  attpool_k<<<80, 256, 0, stream>>>(ws+O_AF1, ws+S_GC1, ws+S_P1, N);
  attpool_k<<<80, 256, 0, stream>>>(ws+O_AF2, ws+S_GC2, ws+S_P2, N);

  // tensor-network scores
  s0_k<<<1, 64, 0, stream>>>(ws+S_P1, ws+S_P2, tn_w, tn_wb, tn_bias, ws+S_S0);
  bbuild_k<<<1, 512, 0, stream>>>(ws+S_P2, tn_w, tn_wb, tn_bias, ws+S_B, ws+S_C);
  tnmean_k<<<80, 256, 0, stream>>>(ws+O_AF1, ws+S_B, ws+S_C, ws+S_S1ACC, N);
  bbuild_k<<<1, 512, 0, stream>>>(ws+S_P1, tn_w, tn_wb, tn_bias, ws+S_B, ws+S_C);
  tnmean_k<<<80, 256, 0, stream>>>(ws+O_AF2, ws+S_B, ws+S_C, ws+S_S2ACC, N);

  // head
  final_k<<<1, 64, 0, stream>>>(ws, ghist, fc1_w, fc1_b, fc2_w, fc2_b, out);
}

// Round 2
// 1957.861 us; speedup vs baseline: 1.7265x; 1.7265x over previous
//
#include <hip/hip_runtime.h>
#include <math.h>

#define N_NODES 10000
#define E_      320000
#define NT2     79                  // ceil(10000/128)
#define NPAD2   (NT2*128)           // 10112

// ---- workspace layout (float offsets) ----
#define S_CSUM1 0
#define S_CSUM2 32
#define S_GC1   64
#define S_GC2   96
#define S_P1    128
#define S_P2    160
#define S_S1ACC 192
#define S_S2ACC 208
#define S_S0    224
#define S_B     240               // 512
#define S_C     752               // 16
#define S_HIST  768               // 64*16 u32 -> [768,1792)
#define ZERO_SMALL 1792
#define O_MINMAX 1792             // 2 u32 (special init)
#define O_DINV  1800              // 10000 (per-graph, reused)
#define O_INV   11800             // 10000
#define O_OFF   21800             // 10001 ints
#define O_CUR   31804             // 10000 ints
#define O_SRC   41804             // 320000 ints
#define O_BUFH  361804            // N*128
#define O_BUFO  1641804           // N*128
#define O_AF1   2921804           // NPAD2*32 = 323584
#define O_AF2   3245388           // NPAD2*32
// end: 3568972 floats = 14.3 MB

__device__ __forceinline__ unsigned f2ord(float f){
  unsigned u = __float_as_uint(f);
  return (u & 0x80000000u) ? ~u : (u | 0x80000000u);
}
__device__ __forceinline__ float ord2f(unsigned u){
  return (u & 0x80000000u) ? __uint_as_float(u & 0x7FFFFFFFu) : __uint_as_float(~u);
}

__global__ void init_k(float* ws){
  int i = blockIdx.x*blockDim.x + threadIdx.x;
  if(i < ZERO_SMALL) ws[i] = 0.f;
  if(blockIdx.x==0 && threadIdx.x==0){
    unsigned* mm = (unsigned*)(ws + O_MINMAX);
    mm[0] = 0xFFFFFFFFu;
    mm[1] = 0u;
  }
}

__global__ void zero_k(float* p, int n){
  int i = blockIdx.x*blockDim.x + threadIdx.x;
  if(i < n) p[i] = 0.f;
}

__global__ void deg_k(const int* __restrict__ dst, float* __restrict__ degc, int E){
  int i = blockIdx.x*blockDim.x + threadIdx.x;
  if(i < E) atomicAdd(&degc[dst[i]], 1.0f);
}

// single block: exclusive scan of float degree counts -> off[n+1], cursor[n]
__global__ void scan_k(const float* __restrict__ degf, int* __restrict__ off,
                       int* __restrict__ cur, int n){
  __shared__ int part[256];
  int t = threadIdx.x;
  int chunk = (n + 255)/256;
  int start = t*chunk, end = min(start+chunk, n);
  int s = 0;
  for(int i=start;i<end;i++) s += (int)degf[i];
  part[t] = s; __syncthreads();
  if(t==0){
    int run = 0;
    for(int i=0;i<256;i++){ int v=part[i]; part[i]=run; run+=v; }
  }
  __syncthreads();
  int run = part[t];
  for(int i=start;i<end;i++){
    off[i]=run; cur[i]=run; run += (int)degf[i];
  }
  if(end==n) off[n]=run;
}

__global__ void degfin_k(float* __restrict__ dinv, float* __restrict__ inv, int n){
  int i = blockIdx.x*blockDim.x + threadIdx.x;
  if(i < n){
    float d = dinv[i] + 1.0f;
    dinv[i] = 1.0f/sqrtf(d);
    inv[i]  = 1.0f/d;
  }
}

__global__ void bucket_k(const int* __restrict__ src, const int* __restrict__ dst,
                         int* __restrict__ cur, int* __restrict__ srcs, int E){
  int e = blockIdx.x*blockDim.x + threadIdx.x;
  if(e < E){
    int d = dst[e];
    int pos = atomicAdd(&cur[d], 1);
    srcs[pos] = src[e];
  }
}

// C[n,FOUT] = act(A[n,FIN]) @ W[FIN,FOUT], 4 outputs/thread
template<int FIN, int FOUT, bool RELU>
__global__ __launch_bounds__(256) void gemm_k(const float* __restrict__ A,
                                              const float* __restrict__ W,
                                              float* __restrict__ C, int n){
  constexpr int KC  = (FIN > 64) ? 64 : FIN;
  constexpr int TPR = FOUT/4;              // threads per row
  constexpr int ROWS = 256/TPR;
  __shared__ float4 Ws[KC*TPR];
  int row = blockIdx.x*ROWS + (int)threadIdx.x/TPR;
  int c4  = threadIdx.x % TPR;
  float4 acc = {0.f,0.f,0.f,0.f};
  const float4* W4 = (const float4*)W;
  for(int kc=0; kc<FIN; kc+=KC){
    __syncthreads();
    for(int t=threadIdx.x; t<KC*TPR; t+=256) Ws[t] = W4[(size_t)kc*TPR + t];
    __syncthreads();
    if(row < n){
      const float* a = A + (size_t)row*FIN + kc;
      #pragma unroll
      for(int k=0;k<KC;k++){
        float v = a[k];
        if(RELU) v = fmaxf(v, 0.f);
        float4 w = Ws[k*TPR + c4];
        acc.x = fmaf(v, w.x, acc.x);
        acc.y = fmaf(v, w.y, acc.y);
        acc.z = fmaf(v, w.z, acc.z);
        acc.w = fmaf(v, w.w, acc.w);
      }
    }
  }
  if(row < n) ((float4*)C)[(size_t)row*TPR + c4] = acc;
}

// fused neighbor-gather + self + bias: out[d] = b + h[d]*inv[d] + sum coef*h[src]
template<int F>
__global__ __launch_bounds__(256) void aggr_k(const float* __restrict__ h,
                                              const int* __restrict__ off,
                                              const int* __restrict__ srcs,
                                              const float* __restrict__ dinv,
                                              const float* __restrict__ inv,
                                              const float* __restrict__ bias,
                                              float* __restrict__ out, int n){
  constexpr int G = F/4;
  constexpr int NPB = 256/G;
  int node = blockIdx.x*NPB + (int)threadIdx.x/G;
  int g = threadIdx.x % G;
  if(node >= n) return;
  const float4* h4 = (const float4*)h;
  float4 b4 = ((const float4*)bias)[g];
  float4 hv = h4[(size_t)node*G + g];
  float iv = inv[node];
  float dd = dinv[node];
  float4 acc;
  acc.x = fmaf(hv.x, iv, b4.x);
  acc.y = fmaf(hv.y, iv, b4.y);
  acc.z = fmaf(hv.z, iv, b4.z);
  acc.w = fmaf(hv.w, iv, b4.w);
  int p0 = off[node], p1 = off[node+1];
  for(int p=p0; p<p1; ++p){
    int s = srcs[p];
    float c = dinv[s]*dd;
    float4 v = h4[(size_t)s*G + g];
    acc.x = fmaf(c, v.x, acc.x);
    acc.y = fmaf(c, v.y, acc.y);
    acc.z = fmaf(c, v.z, acc.z);
    acc.w = fmaf(c, v.w, acc.w);
  }
  ((float4*)out)[(size_t)node*G + g] = acc;
}

// 128x128 tile, 8x8 microtile. Row-major swizzled tiles:
// float4 of (row, k4) stored at T[row*32 + ((((k4>>2)+(row>>3))&7)<<2)]
template<bool HIST>
__global__ __launch_bounds__(256) void sim_k(const float* __restrict__ af1,
                                             const float* __restrict__ af2,
                                             unsigned* __restrict__ minmax,
                                             unsigned* __restrict__ ghist){
  __shared__ __align__(16) float ta[128*32], tb[128*32];
  __shared__ unsigned lh[64*17];
  int bx = blockIdx.x % NT2, by = blockIdx.x / NT2;
  int i0 = by*128, j0 = bx*128;
  {
    int row = threadIdx.x & 127;
    int ch  = threadIdx.x >> 7;
    #pragma unroll
    for(int cc=0; cc<8; cc+=2){
      int chunk = ch + cc;
      int pos = ((chunk + (row>>3)) & 7) << 2;
      *(float4*)&ta[row*32 + pos] = *(const float4*)&af1[(size_t)(i0+row)*32 + chunk*4];
      *(float4*)&tb[row*32 + pos] = *(const float4*)&af2[(size_t)(j0+row)*32 + chunk*4];
    }
  }
  if(HIST){ for(int t=threadIdx.x; t<64*17; t+=256) lh[t]=0u; }
  __syncthreads();
  int tx = threadIdx.x & 15, ty = threadIdx.x >> 4;
  float acc[8][8];
  #pragma unroll
  for(int r=0;r<8;r++)
    #pragma unroll
    for(int c=0;c<8;c++) acc[r][c]=0.f;
  #pragma unroll
  for(int kk=0; kk<32; kk+=4){
    int kc = kk>>2;
    float4 a[8];
    int apos = ((kc + ty) & 7) << 2;
    #pragma unroll
    for(int r=0;r<8;r++) a[r] = *(float4*)&ta[(ty*8+r)*32 + apos];
    int bpos = ((kc + tx) & 7) << 2;
    #pragma unroll
    for(int c=0;c<8;c++){
      float4 b = *(float4*)&tb[(tx*8+c)*32 + bpos];
      #pragma unroll
      for(int r=0;r<8;r++){
        float v = acc[r][c];
        v = fmaf(a[r].x, b.x, v);
        v = fmaf(a[r].y, b.y, v);
        v = fmaf(a[r].z, b.z, v);
        v = fmaf(a[r].w, b.w, v);
        acc[r][c] = v;
      }
    }
  }
  if(!HIST){
    float m = INFINITY, M = -INFINITY;
    #pragma unroll
    for(int r=0;r<8;r++){
      if(i0+ty*8+r >= N_NODES) continue;
      #pragma unroll
      for(int c=0;c<8;c++){
        if(j0+tx*8+c >= N_NODES) continue;
        float v = acc[r][c];
        m = fminf(m, v); M = fmaxf(M, v);
      }
    }
    #pragma unroll
    for(int off=32; off; off>>=1){
      m = fminf(m, __shfl_down(m, off, 64));
      M = fmaxf(M, __shfl_down(M, off, 64));
    }
    if((threadIdx.x & 63)==0){
      atomicMin(&minmax[0], f2ord(m));
      atomicMax(&minmax[1], f2ord(M));
    }
  } else {
    float lo = ord2f(minmax[0]);
    float hi = ord2f(minmax[1]);
    float denom = (hi-lo) + 1e-12f;
    unsigned base = (threadIdx.x & 63)*17;
    #pragma unroll
    for(int r=0;r<8;r++){
      if(i0+ty*8+r >= N_NODES) continue;
      #pragma unroll
      for(int c=0;c<8;c++){
        if(j0+tx*8+c >= N_NODES) continue;
        int idx = (int)((acc[r][c]-lo)/denom*16.0f);   // match reference op order
        idx = idx<0 ? 0 : (idx>15 ? 15 : idx);
        atomicAdd(&lh[base+idx], 1u);
      }
    }
    __syncthreads();
    if(threadIdx.x<16){
      unsigned s=0;
      for(int c2=0;c2<64;c2++) s += lh[c2*17+threadIdx.x];
      atomicAdd(&ghist[(blockIdx.x & 63)*16 + threadIdx.x], s);
    }
  }
}

__global__ void colsum_k(const float* __restrict__ af, float* __restrict__ csum, int n){
  int f = threadIdx.x % 32;
  int rg = threadIdx.x / 32;
  float acc = 0.f;
  for(int node = blockIdx.x*8 + rg; node < n; node += gridDim.x*8)
    acc += af[(size_t)node*32 + f];
  __shared__ float s[256];
  s[threadIdx.x]=acc; __syncthreads();
  if(threadIdx.x<32){
    float v=0.f;
    for(int r=0;r<8;r++) v += s[r*32+threadIdx.x];
    atomicAdd(&csum[threadIdx.x], v);
  }
}

__global__ void gc_k(const float* __restrict__ csum, const float* __restrict__ att_w,
                     float* __restrict__ gc){
  int j = threadIdx.x;
  if(j < 32){
    float acc = 0.f;
    for(int f=0;f<32;f++) acc += csum[f]*att_w[f*32+j];
    gc[j] = tanhf(acc * (1.0f/N_NODES));
  }
}

__global__ __launch_bounds__(256) void attpool_k(const float* __restrict__ af,
                                                 const float* __restrict__ gc,
                                                 float* __restrict__ p, int n){
  __shared__ float sgc[32];
  if(threadIdx.x<32) sgc[threadIdx.x]=gc[threadIdx.x];
  __syncthreads();
  float pacc[32];
  #pragma unroll
  for(int f=0;f<32;f++) pacc[f]=0.f;
  for(int node = blockIdx.x*blockDim.x + threadIdx.x; node < n; node += gridDim.x*blockDim.x){
    const float* row = af + (size_t)node*32;
    float d = 0.f;
    #pragma unroll
    for(int f=0;f<32;f++) d += row[f]*sgc[f];
    float sig = 1.0f/(1.0f+expf(-d));
    #pragma unroll
    for(int f=0;f<32;f++) pacc[f] += row[f]*sig;
  }
  #pragma unroll
  for(int f=0;f<32;f++){
    float v = pacc[f];
    for(int off=32; off; off>>=1) v += __shfl_down(v, off, 64);
    if((threadIdx.x & 63)==0) atomicAdd(&p[f], v);
  }
}

__global__ void s0_k(const float* __restrict__ p1, const float* __restrict__ p2,
                     const float* __restrict__ tn_w, const float* __restrict__ tn_wb,
                     const float* __restrict__ tn_bias, float* __restrict__ s0out){
  int k = threadIdx.x;
  if(k < 16){
    float s = 0.f;
    for(int f1=0;f1<32;f1++){
      float a = p1[f1];
      for(int f2=0;f2<32;f2++) s += a*tn_w[(f1*32+f2)*16+k]*p2[f2];
    }
    float blk = 0.f;
    for(int f=0;f<32;f++) blk += tn_wb[k*64+f]*p1[f] + tn_wb[k*64+32+f]*p2[f];
    s0out[k] = fmaxf(s + blk + tn_bias[k], 0.f);
  }
}

__global__ void bbuild_k(const float* __restrict__ pv, const float* __restrict__ tn_w,
                         const float* __restrict__ tn_wb, const float* __restrict__ tn_bias,
                         float* __restrict__ B, float* __restrict__ c){
  int t = threadIdx.x;
  if(t < 512){
    int g = t/16, k = t%16;
    float acc = 0.f;
    for(int f=0;f<32;f++) acc += tn_w[(g*32+f)*16+k]*pv[f];
    B[t] = acc + tn_wb[k*64+g];
  }
  if(t < 16){
    float acc = 0.f;
    for(int f=0;f<32;f++) acc += tn_wb[t*64+32+f]*pv[f];
    c[t] = acc + tn_bias[t];
  }
}

__global__ __launch_bounds__(256) void tnmean_k(const float* __restrict__ X,
                                                const float* __restrict__ B,
                                                const float* __restrict__ c,
                                                float* __restrict__ acc, int n){
  __shared__ float sB[512];
  __shared__ float sc[16];
  for(int i=threadIdx.x;i<512;i+=256) sB[i]=B[i];
  if(threadIdx.x<16) sc[threadIdx.x]=c[threadIdx.x];
  __syncthreads();
  float a[16];
  #pragma unroll
  for(int k=0;k<16;k++) a[k]=0.f;
  for(int node = blockIdx.x*blockDim.x + threadIdx.x; node < n; node += gridDim.x*blockDim.x){
    const float* row = X + (size_t)node*32;
    float rv[32];
    #pragma unroll
    for(int g=0;g<32;g++) rv[g]=row[g];
    #pragma unroll
    for(int k=0;k<16;k++){
      float y = sc[k];
      #pragma unroll
      for(int g=0;g<32;g++) y += rv[g]*sB[g*16+k];
      a[k] += fmaxf(y, 0.f);
    }
  }
  #pragma unroll
  for(int k=0;k<16;k++){
    float v = a[k];
    for(int off=32; off; off>>=1) v += __shfl_down(v, off, 64);
    if((threadIdx.x & 63)==0) atomicAdd(&acc[k], v);
  }
}

__global__ void final_k(const float* __restrict__ ws, const unsigned* __restrict__ ghist,
                        const float* __restrict__ fc1_w, const float* __restrict__ fc1_b,
                        const float* __restrict__ fc2_w, const float* __restrict__ fc2_b,
                        float* __restrict__ out){
  if(threadIdx.x != 0 || blockIdx.x != 0) return;
  float scores[64];
  const float invN = 1.0f/N_NODES;
  for(int k=0;k<16;k++) scores[k]      = ws[S_S0+k];
  for(int k=0;k<16;k++) scores[16+k]   = ws[S_S1ACC+k]*invN;
  for(int k=0;k<16;k++) scores[32+k]   = ws[S_S2ACC+k]*invN;
  float tot = 0.f, hv[16];
  for(int b=0;b<16;b++){
    unsigned cnt = 0;
    for(int c=0;c<64;c++) cnt += ghist[c*16+b];
    float v = (float)cnt;
    if(v > 16777216.0f) v = 16777216.0f;   // fp32 +1.0 saturation emulation
    hv[b]=v; tot+=v;
  }
  for(int b=0;b<16;b++) scores[48+b] = hv[b]/tot;
  float h[16];
  for(int j=0;j<16;j++){
    float a = fc1_b[j];
    for(int i=0;i<64;i++) a += scores[i]*fc1_w[i*16+j];
    h[j] = fmaxf(a, 0.f);
  }
  float o = fc2_b[0];
  for(int j=0;j<16;j++) o += h[j]*fc2_w[j];
  out[0] = 1.0f/(1.0f+expf(-o));
}

extern "C" void kernel_launch(void* const* d_in, const int* in_sizes, int n_in,
                              void* d_out, int out_size, void* d_ws, size_t ws_size,
                              hipStream_t stream){
  const float* x1      = (const float*)d_in[0];
  const float* x2      = (const float*)d_in[1];
  const int*   ei1     = (const int*)d_in[2];
  const int*   ei2     = (const int*)d_in[3];
  const float* W1      = (const float*)d_in[4];
  const float* b1      = (const float*)d_in[5];
  const float* W2      = (const float*)d_in[6];
  const float* b2      = (const float*)d_in[7];
  const float* W3      = (const float*)d_in[8];
  const float* b3      = (const float*)d_in[9];
  const float* att_w   = (const float*)d_in[10];
  const float* tn_w    = (const float*)d_in[11];
  const float* tn_wb   = (const float*)d_in[12];
  const float* tn_bias = (const float*)d_in[13];
  const float* fc1_w   = (const float*)d_in[14];
  const float* fc1_b   = (const float*)d_in[15];
  const float* fc2_w   = (const float*)d_in[16];
  const float* fc2_b   = (const float*)d_in[17];

  float* ws = (float*)d_ws;
  float* out = (float*)d_out;
  const int N = N_NODES, E = E_;

  unsigned* minmax = (unsigned*)(ws + O_MINMAX);
  unsigned* ghist  = (unsigned*)(ws + S_HIST);
  int* off  = (int*)(ws + O_OFF);
  int* cur  = (int*)(ws + O_CUR);
  int* srcs = (int*)(ws + O_SRC);

  init_k<<<(ZERO_SMALL+255)/256, 256, 0, stream>>>(ws);

  for(int g=0; g<2; g++){
    const float* x = g ? x2 : x1;
    const int* src = (g ? ei2 : ei1);
    const int* dst = src + E;
    float* dinv = ws + O_DINV;
    float* inv  = ws + O_INV;
    float* af   = ws + (g ? O_AF2 : O_AF1);
    float* bufH = ws + O_BUFH;
    float* bufO = ws + O_BUFO;

    // CSR build (reused for 3 layers)
    zero_k<<<(N+255)/256, 256, 0, stream>>>(dinv, N);
    deg_k<<<(E+255)/256, 256, 0, stream>>>(dst, dinv, E);
    scan_k<<<1, 256, 0, stream>>>(dinv, off, cur, N);
    degfin_k<<<(N+255)/256, 256, 0, stream>>>(dinv, inv, N);
    bucket_k<<<(E+255)/256, 256, 0, stream>>>(src, dst, cur, srcs, E);

    // layer 1: 128 -> 128
    gemm_k<128,128,false><<<(N+7)/8, 256, 0, stream>>>(x, W1, bufH, N);
    aggr_k<128><<<(N+7)/8, 256, 0, stream>>>(bufH, off, srcs, dinv, inv, b1, bufO, N);
    // layer 2: 128 -> 64
    gemm_k<128,64,true><<<(N+15)/16, 256, 0, stream>>>(bufO, W2, bufH, N);
    aggr_k<64><<<(N+15)/16, 256, 0, stream>>>(bufH, off, srcs, dinv, inv, b2, bufO, N);
    // layer 3: 64 -> 32
    gemm_k<64,32,true><<<(N+31)/32, 256, 0, stream>>>(bufO, W3, bufH, N);
    aggr_k<32><<<(N+31)/32, 256, 0, stream>>>(bufH, off, srcs, dinv, inv, b3, af, N);
  }

  // similarity: min/max pass then histogram pass
  sim_k<false><<<NT2*NT2, 256, 0, stream>>>(ws+O_AF1, ws+O_AF2, minmax, ghist);
  sim_k<true ><<<NT2*NT2, 256, 0, stream>>>(ws+O_AF1, ws+O_AF2, minmax, ghist);

  // attention pooling
  colsum_k<<<64, 256, 0, stream>>>(ws+O_AF1, ws+S_CSUM1, N);
  colsum_k<<<64, 256, 0, stream>>>(ws+O_AF2, ws+S_CSUM2, N);
  gc_k<<<1, 64, 0, stream>>>(ws+S_CSUM1, att_w, ws+S_GC1);
  gc_k<<<1, 64, 0, stream>>>(ws+S_CSUM2, att_w, ws+S_GC2);
  attpool_k<<<80, 256, 0, stream>>>(ws+O_AF1, ws+S_GC1, ws+S_P1, N);
  attpool_k<<<80, 256, 0, stream>>>(ws+O_AF2, ws+S_GC2, ws+S_P2, N);

  // tensor-network scores
  s0_k<<<1, 64, 0, stream>>>(ws+S_P1, ws+S_P2, tn_w, tn_wb, tn_bias, ws+S_S0);
  bbuild_k<<<1, 512, 0, stream>>>(ws+S_P2, tn_w, tn_wb, tn_bias, ws+S_B, ws+S_C);
  tnmean_k<<<80, 256, 0, stream>>>(ws+O_AF1, ws+S_B, ws+S_C, ws+S_S1ACC, N);
  bbuild_k<<<1, 512, 0, stream>>>(ws+S_P1, tn_w, tn_wb, tn_bias, ws+S_B, ws+S_C);
  tnmean_k<<<80, 256, 0, stream>>>(ws+O_AF2, ws+S_B, ws+S_C, ws+S_S2ACC, N);

  // head
  final_k<<<1, 64, 0, stream>>>(ws, ghist, fc1_w, fc1_b, fc2_w, fc2_b, out);
}

// Round 3
// 1169.625 us; speedup vs baseline: 2.8900x; 1.6739x over previous
//
#include <hip/hip_runtime.h>
#include <math.h>

#define N_NODES 10000
#define E_      320000
#define NT2     79                  // ceil(10000/128)
#define NPAD2   (NT2*128)           // 10112
#define PADK    36                  // tile row stride (floats)

// ---- workspace layout (float offsets) ----
#define S_CSUM1 0
#define S_CSUM2 32
#define S_GC1   64
#define S_GC2   96
#define S_P1    128
#define S_P2    160
#define S_S1ACC 192
#define S_S2ACC 208
#define S_S0    224
#define S_B     240               // 512
#define S_C     752               // 16
#define S_HIST  768               // 64*16 u32 -> [768,1792)
#define ZERO_SMALL 1792
#define S_MMSLOT 1792             // 128 u32 (min[64], max[64])
#define S_MM     1920             // 2 u32
#define O_DINV  2048              // 10000 (per-graph, reused)
#define O_INV   12048             // 10000
#define O_OFF   22048             // 10001 ints
#define O_CUR   32052             // 10000 ints
#define O_SRC   42052             // 320000 ints
#define O_BUFH  362052            // N*128
#define O_BUFO  1642052           // N*128
#define O_AF1   2922052           // NPAD2*32 = 323584
#define O_AF2   3245636
// end: 3569220 floats ~= 14.28 MB (same footprint as proven rounds)

__device__ __forceinline__ unsigned f2ord(float f){
  unsigned u = __float_as_uint(f);
  return (u & 0x80000000u) ? ~u : (u | 0x80000000u);
}
__device__ __forceinline__ float ord2f(unsigned u){
  return (u & 0x80000000u) ? __uint_as_float(u & 0x7FFFFFFFu) : __uint_as_float(~u);
}

__global__ void init_k(float* ws){
  int i = blockIdx.x*blockDim.x + threadIdx.x;
  if(i < ZERO_SMALL) ws[i] = 0.f;
  if(i < 128){
    unsigned* sl = (unsigned*)(ws + S_MMSLOT);
    sl[i] = (i < 64) ? 0xFFFFFFFFu : 0u;
  }
  if(i < 2){
    unsigned* mm = (unsigned*)(ws + S_MM);
    mm[i] = (i==0) ? 0xFFFFFFFFu : 0u;
  }
  if(i < (NPAD2 - N_NODES)*32){     // zero af pad rows
    ws[O_AF1 + N_NODES*32 + i] = 0.f;
    ws[O_AF2 + N_NODES*32 + i] = 0.f;
  }
}

__global__ void zero_k(float* p, int n){
  int i = blockIdx.x*blockDim.x + threadIdx.x;
  if(i < n) p[i] = 0.f;
}

__global__ void deg_k(const int* __restrict__ dst, float* __restrict__ degc, int E){
  int i = blockIdx.x*blockDim.x + threadIdx.x;
  if(i < E) atomicAdd(&degc[dst[i]], 1.0f);
}

// single block: exclusive scan of float degree counts -> off[n+1], cursor[n]
__global__ void scan_k(const float* __restrict__ degf, int* __restrict__ off,
                       int* __restrict__ cur, int n){
  __shared__ int part[256];
  int t = threadIdx.x;
  int chunk = (n + 255)/256;
  int start = t*chunk, end = min(start+chunk, n);
  int s = 0;
  for(int i=start;i<end;i++) s += (int)degf[i];
  part[t] = s; __syncthreads();
  if(t==0){
    int run = 0;
    for(int i=0;i<256;i++){ int v=part[i]; part[i]=run; run+=v; }
  }
  __syncthreads();
  int run = part[t];
  for(int i=start;i<end;i++){
    off[i]=run; cur[i]=run; run += (int)degf[i];
  }
  if(end==n) off[n]=run;
}

__global__ void degfin_k(float* __restrict__ dinv, float* __restrict__ inv, int n){
  int i = blockIdx.x*blockDim.x + threadIdx.x;
  if(i < n){
    float d = dinv[i] + 1.0f;
    dinv[i] = 1.0f/sqrtf(d);
    inv[i]  = 1.0f/d;
  }
}

__global__ void bucket_k(const int* __restrict__ src, const int* __restrict__ dst,
                         int* __restrict__ cur, int* __restrict__ srcs, int E){
  int e = blockIdx.x*blockDim.x + threadIdx.x;
  if(e < E){
    int d = dst[e];
    int pos = atomicAdd(&cur[d], 1);
    srcs[pos] = src[e];
  }
}

// C[n,FOUT] = act(A[n,FIN]) @ W[FIN,FOUT], 4 outputs/thread
template<int FIN, int FOUT, bool RELU>
__global__ __launch_bounds__(256) void gemm_k(const float* __restrict__ A,
                                              const float* __restrict__ W,
                                              float* __restrict__ C, int n){
  constexpr int KC  = (FIN > 64) ? 64 : FIN;
  constexpr int TPR = FOUT/4;              // threads per row
  constexpr int ROWS = 256/TPR;
  __shared__ float4 Ws[KC*TPR];
  int row = blockIdx.x*ROWS + (int)threadIdx.x/TPR;
  int c4  = threadIdx.x % TPR;
  float4 acc = {0.f,0.f,0.f,0.f};
  const float4* W4 = (const float4*)W;
  for(int kc=0; kc<FIN; kc+=KC){
    __syncthreads();
    for(int t=threadIdx.x; t<KC*TPR; t+=256) Ws[t] = W4[(size_t)kc*TPR + t];
    __syncthreads();
    if(row < n){
      const float* a = A + (size_t)row*FIN + kc;
      #pragma unroll
      for(int k=0;k<KC;k++){
        float v = a[k];
        if(RELU) v = fmaxf(v, 0.f);
        float4 w = Ws[k*TPR + c4];
        acc.x = fmaf(v, w.x, acc.x);
        acc.y = fmaf(v, w.y, acc.y);
        acc.z = fmaf(v, w.z, acc.z);
        acc.w = fmaf(v, w.w, acc.w);
      }
    }
  }
  if(row < n) ((float4*)C)[(size_t)row*TPR + c4] = acc;
}

// fused gather-aggregation: out[d] = b + h[d]*inv[d] + sum_{s in N(d)} dinv[s]*dinv[d]*h[s]
// Subgroup of G=F/4 lanes per node; edge (src,coef) loaded in parallel then
// broadcast via shfl so h-gathers have no serial address dependency.
template<int F>
__global__ __launch_bounds__(256) void aggr_k(const float* __restrict__ h,
                                              const int* __restrict__ off,
                                              const int* __restrict__ srcs,
                                              const float* __restrict__ dinv,
                                              const float* __restrict__ inv,
                                              const float* __restrict__ bias,
                                              float* __restrict__ out, int n){
  constexpr int G = F/4;
  constexpr int NPB = 256/G;
  int node = blockIdx.x*NPB + (int)threadIdx.x/G;
  int g = threadIdx.x % G;
  if(node >= n) return;
  const float4* h4 = (const float4*)h;
  float4 b4 = ((const float4*)bias)[g];
  float4 hv = h4[(size_t)node*G + g];
  float iv = inv[node];
  float dd = dinv[node];
  float4 acc;
  acc.x = fmaf(hv.x, iv, b4.x);
  acc.y = fmaf(hv.y, iv, b4.y);
  acc.z = fmaf(hv.z, iv, b4.z);
  acc.w = fmaf(hv.w, iv, b4.w);
  int p0 = off[node], p1 = off[node+1];
  for(int base=p0; base<p1; base+=G){
    int idx = base + g;
    int sv = 0; float cv = 0.f;
    if(idx < p1){ sv = srcs[idx]; cv = dinv[sv]*dd; }
    int cnt = min(G, p1-base);
    #pragma unroll 8
    for(int i=0;i<cnt;i++){
      int   si = __shfl(sv, i, G);
      float ci = __shfl(cv, i, G);
      float4 v = h4[(size_t)si*G + g];
      acc.x = fmaf(ci, v.x, acc.x);
      acc.y = fmaf(ci, v.y, acc.y);
      acc.z = fmaf(ci, v.z, acc.z);
      acc.w = fmaf(ci, v.w, acc.w);
    }
  }
  ((float4*)out)[(size_t)node*G + g] = acc;
}

// 128x128 tile, 8x8 microtile, tiles padded to stride 36 (bank-clean b128 reads)
template<bool HIST>
__global__ __launch_bounds__(256,3) void sim_k(const float* __restrict__ af1,
                                               const float* __restrict__ af2,
                                               unsigned* __restrict__ mmslot,
                                               const unsigned* __restrict__ mm,
                                               unsigned* __restrict__ ghist){
  __shared__ __align__(16) float ta[128*PADK];
  __shared__ __align__(16) float tb[128*PADK];
  __shared__ unsigned lh[64*17];
  int bx = blockIdx.x % NT2, by = blockIdx.x / NT2;
  int i0 = by*128, j0 = bx*128;
  {
    int row  = threadIdx.x & 127;
    int half = (threadIdx.x >> 7) * 4;
    const float4* A4 = (const float4*)(af1 + (size_t)(i0+row)*32);
    const float4* B4 = (const float4*)(af2 + (size_t)(j0+row)*32);
    float4* tar = (float4*)(ta + row*PADK);
    float4* tbr = (float4*)(tb + row*PADK);
    #pragma unroll
    for(int j=0;j<4;j++){ tar[half+j] = A4[half+j]; tbr[half+j] = B4[half+j]; }
  }
  if(HIST){ for(int t=threadIdx.x; t<64*17; t+=256) lh[t]=0u; }
  __syncthreads();
  int tx = threadIdx.x & 15, ty = threadIdx.x >> 4;
  float acc[8][8];
  #pragma unroll
  for(int r=0;r<8;r++)
    #pragma unroll
    for(int c=0;c<8;c++) acc[r][c]=0.f;
  #pragma unroll 1
  for(int kk=0; kk<32; kk+=4){
    float4 a[8], b[8];
    #pragma unroll
    for(int r=0;r<8;r++) a[r] = *(const float4*)(ta + (ty+16*r)*PADK + kk);
    #pragma unroll
    for(int c=0;c<8;c++) b[c] = *(const float4*)(tb + (tx+16*c)*PADK + kk);
    #pragma unroll
    for(int r=0;r<8;r++){
      #pragma unroll
      for(int c=0;c<8;c++){
        float v = acc[r][c];
        v = fmaf(a[r].x, b[c].x, v);
        v = fmaf(a[r].y, b[c].y, v);
        v = fmaf(a[r].z, b[c].z, v);
        v = fmaf(a[r].w, b[c].w, v);
        acc[r][c] = v;
      }
    }
  }
  bool full = (i0+128 <= N_NODES) && (j0+128 <= N_NODES);
  if(!HIST){
    float m = INFINITY, M = -INFINITY;
    if(full){
      #pragma unroll
      for(int r=0;r<8;r++)
        #pragma unroll
        for(int c=0;c<8;c++){ float v=acc[r][c]; m=fminf(m,v); M=fmaxf(M,v); }
    } else {
      for(int r=0;r<8;r++){
        if(i0+ty+16*r >= N_NODES) continue;
        for(int c=0;c<8;c++){
          if(j0+tx+16*c >= N_NODES) continue;
          float v=acc[r][c]; m=fminf(m,v); M=fmaxf(M,v);
        }
      }
    }
    #pragma unroll
    for(int off=32; off; off>>=1){
      m = fminf(m, __shfl_down(m, off, 64));
      M = fmaxf(M, __shfl_down(M, off, 64));
    }
    if((threadIdx.x & 63)==0){
      int slot = (blockIdx.x*4 + (threadIdx.x>>6)) & 63;
      atomicMin(&mmslot[slot],      f2ord(m));
      atomicMax(&mmslot[64+slot],   f2ord(M));
    }
  } else {
    float lo = ord2f(mm[0]);
    float hi = ord2f(mm[1]);
    float denom = (hi-lo) + 1e-12f;
    unsigned base = (threadIdx.x & 63)*17;
    if(full){
      #pragma unroll
      for(int r=0;r<8;r++)
        #pragma unroll
        for(int c=0;c<8;c++){
          int idx = (int)((acc[r][c]-lo)/denom*16.0f);   // exact reference op order
          idx = idx<0 ? 0 : (idx>15 ? 15 : idx);
          atomicAdd(&lh[base+idx], 1u);
        }
    } else {
      for(int r=0;r<8;r++){
        if(i0+ty+16*r >= N_NODES) continue;
        for(int c=0;c<8;c++){
          if(j0+tx+16*c >= N_NODES) continue;
          int idx = (int)((acc[r][c]-lo)/denom*16.0f);
          idx = idx<0 ? 0 : (idx>15 ? 15 : idx);
          atomicAdd(&lh[base+idx], 1u);
        }
      }
    }
    __syncthreads();
    if(threadIdx.x<16){
      unsigned s=0;
      for(int w=0;w<64;w++) s += lh[w*17+threadIdx.x];
      atomicAdd(&ghist[(blockIdx.x & 63)*16 + threadIdx.x], s);
    }
  }
}

__global__ void mmred_k(float* ws){
  unsigned* sl = (unsigned*)(ws + S_MMSLOT);
  unsigned* mm = (unsigned*)(ws + S_MM);
  int t = threadIdx.x;   // 64 threads
  unsigned mn = sl[t], mx = sl[64+t];
  #pragma unroll
  for(int off=32; off; off>>=1){
    mn = min(mn, (unsigned)__shfl_down((int)mn, off, 64));
    mx = max(mx, (unsigned)__shfl_down((int)mx, off, 64));
  }
  if(t==0){ mm[0]=mn; mm[1]=mx; }
}

__global__ void colsum_k(const float* __restrict__ af, float* __restrict__ csum, int n){
  int f = threadIdx.x % 32;
  int rg = threadIdx.x / 32;
  float acc = 0.f;
  for(int node = blockIdx.x*8 + rg; node < n; node += gridDim.x*8)
    acc += af[(size_t)node*32 + f];
  __shared__ float s[256];
  s[threadIdx.x]=acc; __syncthreads();
  if(threadIdx.x<32){
    float v=0.f;
    for(int r=0;r<8;r++) v += s[r*32+threadIdx.x];
    atomicAdd(&csum[threadIdx.x], v);
  }
}

__global__ void gc_k(const float* __restrict__ csum, const float* __restrict__ att_w,
                     float* __restrict__ gc){
  int j = threadIdx.x;
  if(j < 32){
    float acc = 0.f;
    for(int f=0;f<32;f++) acc += csum[f]*att_w[f*32+j];
    gc[j] = tanhf(acc * (1.0f/N_NODES));
  }
}

__global__ __launch_bounds__(256) void attpool_k(const float* __restrict__ af,
                                                 const float* __restrict__ gc,
                                                 float* __restrict__ p, int n){
  __shared__ float sgc[32];
  if(threadIdx.x<32) sgc[threadIdx.x]=gc[threadIdx.x];
  __syncthreads();
  float pacc[32];
  #pragma unroll
  for(int f=0;f<32;f++) pacc[f]=0.f;
  for(int node = blockIdx.x*blockDim.x + threadIdx.x; node < n; node += gridDim.x*blockDim.x){
    const float* row = af + (size_t)node*32;
    float d = 0.f;
    #pragma unroll
    for(int f=0;f<32;f++) d += row[f]*sgc[f];
    float sig = 1.0f/(1.0f+expf(-d));
    #pragma unroll
    for(int f=0;f<32;f++) pacc[f] += row[f]*sig;
  }
  #pragma unroll
  for(int f=0;f<32;f++){
    float v = pacc[f];
    for(int off=32; off; off>>=1) v += __shfl_down(v, off, 64);
    if((threadIdx.x & 63)==0) atomicAdd(&p[f], v);
  }
}

__global__ void s0_k(const float* __restrict__ p1, const float* __restrict__ p2,
                     const float* __restrict__ tn_w, const float* __restrict__ tn_wb,
                     const float* __restrict__ tn_bias, float* __restrict__ s0out){
  int k = threadIdx.x;
  if(k < 16){
    float s = 0.f;
    for(int f1=0;f1<32;f1++){
      float a = p1[f1];
      for(int f2=0;f2<32;f2++) s += a*tn_w[(f1*32+f2)*16+k]*p2[f2];
    }
    float blk = 0.f;
    for(int f=0;f<32;f++) blk += tn_wb[k*64+f]*p1[f] + tn_wb[k*64+32+f]*p2[f];
    s0out[k] = fmaxf(s + blk + tn_bias[k], 0.f);
  }
}

__global__ void bbuild_k(const float* __restrict__ pv, const float* __restrict__ tn_w,
                         const float* __restrict__ tn_wb, const float* __restrict__ tn_bias,
                         float* __restrict__ B, float* __restrict__ c){
  int t = threadIdx.x;
  if(t < 512){
    int g = t/16, k = t%16;
    float acc = 0.f;
    for(int f=0;f<32;f++) acc += tn_w[(g*32+f)*16+k]*pv[f];
    B[t] = acc + tn_wb[k*64+g];
  }
  if(t < 16){
    float acc = 0.f;
    for(int f=0;f<32;f++) acc += tn_wb[t*64+32+f]*pv[f];
    c[t] = acc + tn_bias[t];
  }
}

__global__ __launch_bounds__(256) void tnmean_k(const float* __restrict__ X,
                                                const float* __restrict__ B,
                                                const float* __restrict__ c,
                                                float* __restrict__ acc, int n){
  __shared__ float sB[512];
  __shared__ float sc[16];
  for(int i=threadIdx.x;i<512;i+=256) sB[i]=B[i];
  if(threadIdx.x<16) sc[threadIdx.x]=c[threadIdx.x];
  __syncthreads();
  float a[16];
  #pragma unroll
  for(int k=0;k<16;k++) a[k]=0.f;
  for(int node = blockIdx.x*blockDim.x + threadIdx.x; node < n; node += gridDim.x*blockDim.x){
    const float* row = X + (size_t)node*32;
    float rv[32];
    #pragma unroll
    for(int g=0;g<32;g++) rv[g]=row[g];
    #pragma unroll
    for(int k=0;k<16;k++){
      float y = sc[k];
      #pragma unroll
      for(int g=0;g<32;g++) y += rv[g]*sB[g*16+k];
      a[k] += fmaxf(y, 0.f);
    }
  }
  #pragma unroll
  for(int k=0;k<16;k++){
    float v = a[k];
    for(int off=32; off; off>>=1) v += __shfl_down(v, off, 64);
    if((threadIdx.x & 63)==0) atomicAdd(&acc[k], v);
  }
}

__global__ void final_k(const float* __restrict__ ws, const unsigned* __restrict__ ghist,
                        const float* __restrict__ fc1_w, const float* __restrict__ fc1_b,
                        const float* __restrict__ fc2_w, const float* __restrict__ fc2_b,
                        float* __restrict__ out){
  if(threadIdx.x != 0 || blockIdx.x != 0) return;
  float scores[64];
  const float invN = 1.0f/N_NODES;
  for(int k=0;k<16;k++) scores[k]      = ws[S_S0+k];
  for(int k=0;k<16;k++) scores[16+k]   = ws[S_S1ACC+k]*invN;
  for(int k=0;k<16;k++) scores[32+k]   = ws[S_S2ACC+k]*invN;
  float tot = 0.f, hv[16];
  for(int b=0;b<16;b++){
    unsigned cnt = 0;
    for(int c=0;c<64;c++) cnt += ghist[c*16+b];
    float v = (float)cnt;
    if(v > 16777216.0f) v = 16777216.0f;   // fp32 +1.0 saturation emulation
    hv[b]=v; tot+=v;
  }
  for(int b=0;b<16;b++) scores[48+b] = hv[b]/tot;
  float h[16];
  for(int j=0;j<16;j++){
    float a = fc1_b[j];
    for(int i=0;i<64;i++) a += scores[i]*fc1_w[i*16+j];
    h[j] = fmaxf(a, 0.f);
  }
  float o = fc2_b[0];
  for(int j=0;j<16;j++) o += h[j]*fc2_w[j];
  out[0] = 1.0f/(1.0f+expf(-o));
}

extern "C" void kernel_launch(void* const* d_in, const int* in_sizes, int n_in,
                              void* d_out, int out_size, void* d_ws, size_t ws_size,
                              hipStream_t stream){
  const float* x1      = (const float*)d_in[0];
  const float* x2      = (const float*)d_in[1];
  const int*   ei1     = (const int*)d_in[2];
  const int*   ei2     = (const int*)d_in[3];
  const float* W1      = (const float*)d_in[4];
  const float* b1      = (const float*)d_in[5];
  const float* W2      = (const float*)d_in[6];
  const float* b2      = (const float*)d_in[7];
  const float* W3      = (const float*)d_in[8];
  const float* b3      = (const float*)d_in[9];
  const float* att_w   = (const float*)d_in[10];
  const float* tn_w    = (const float*)d_in[11];
  const float* tn_wb   = (const float*)d_in[12];
  const float* tn_bias = (const float*)d_in[13];
  const float* fc1_w   = (const float*)d_in[14];
  const float* fc1_b   = (const float*)d_in[15];
  const float* fc2_w   = (const float*)d_in[16];
  const float* fc2_b   = (const float*)d_in[17];

  float* ws = (float*)d_ws;
  float* out = (float*)d_out;
  const int N = N_NODES, E = E_;

  unsigned* mmslot = (unsigned*)(ws + S_MMSLOT);
  unsigned* mm     = (unsigned*)(ws + S_MM);
  unsigned* ghist  = (unsigned*)(ws + S_HIST);
  int* off  = (int*)(ws + O_OFF);
  int* cur  = (int*)(ws + O_CUR);
  int* srcs = (int*)(ws + O_SRC);

  init_k<<<((NPAD2-N_NODES)*32+255)/256, 256, 0, stream>>>(ws);

  for(int g=0; g<2; g++){
    const float* x = g ? x2 : x1;
    const int* src = (g ? ei2 : ei1);
    const int* dst = src + E;
    float* dinv = ws + O_DINV;
    float* inv  = ws + O_INV;
    float* af   = ws + (g ? O_AF2 : O_AF1);
    float* bufH = ws + O_BUFH;
    float* bufO = ws + O_BUFO;

    // CSR build (reused for 3 layers)
    zero_k<<<(N+255)/256, 256, 0, stream>>>(dinv, N);
    deg_k<<<(E+255)/256, 256, 0, stream>>>(dst, dinv, E);
    scan_k<<<1, 256, 0, stream>>>(dinv, off, cur, N);
    degfin_k<<<(N+255)/256, 256, 0, stream>>>(dinv, inv, N);
    bucket_k<<<(E+255)/256, 256, 0, stream>>>(src, dst, cur, srcs, E);

    // layer 1: 128 -> 128
    gemm_k<128,128,false><<<(N+7)/8, 256, 0, stream>>>(x, W1, bufH, N);
    aggr_k<128><<<(N+7)/8, 256, 0, stream>>>(bufH, off, srcs, dinv, inv, b1, bufO, N);
    // layer 2: 128 -> 64
    gemm_k<128,64,true><<<(N+15)/16, 256, 0, stream>>>(bufO, W2, bufH, N);
    aggr_k<64><<<(N+15)/16, 256, 0, stream>>>(bufH, off, srcs, dinv, inv, b2, bufO, N);
    // layer 3: 64 -> 32
    gemm_k<64,32,true><<<(N+31)/32, 256, 0, stream>>>(bufO, W3, bufH, N);
    aggr_k<32><<<(N+31)/32, 256, 0, stream>>>(bufH, off, srcs, dinv, inv, b3, af, N);
  }

  // similarity: min/max pass -> slot reduce -> histogram pass
  sim_k<false><<<NT2*NT2, 256, 0, stream>>>(ws+O_AF1, ws+O_AF2, mmslot, mm, ghist);
  mmred_k<<<1, 64, 0, stream>>>(ws);
  sim_k<true ><<<NT2*NT2, 256, 0, stream>>>(ws+O_AF1, ws+O_AF2, mmslot, mm, ghist);

  // attention pooling
  colsum_k<<<64, 256, 0, stream>>>(ws+O_AF1, ws+S_CSUM1, N);
  colsum_k<<<64, 256, 0, stream>>>(ws+O_AF2, ws+S_CSUM2, N);
  gc_k<<<1, 64, 0, stream>>>(ws+S_CSUM1, att_w, ws+S_GC1);
  gc_k<<<1, 64, 0, stream>>>(ws+S_CSUM2, att_w, ws+S_GC2);
  attpool_k<<<80, 256, 0, stream>>>(ws+O_AF1, ws+S_GC1, ws+S_P1, N);
  attpool_k<<<80, 256, 0, stream>>>(ws+O_AF2, ws+S_GC2, ws+S_P2, N);

  // tensor-network scores
  s0_k<<<1, 64, 0, stream>>>(ws+S_P1, ws+S_P2, tn_w, tn_wb, tn_bias, ws+S_S0);
  bbuild_k<<<1, 512, 0, stream>>>(ws+S_P2, tn_w, tn_wb, tn_bias, ws+S_B, ws+S_C);
  tnmean_k<<<80, 256, 0, stream>>>(ws+O_AF1, ws+S_B, ws+S_C, ws+S_S1ACC, N);
  bbuild_k<<<1, 512, 0, stream>>>(ws+S_P1, tn_w, tn_wb, tn_bias, ws+S_B, ws+S_C);
  tnmean_k<<<80, 256, 0, stream>>>(ws+O_AF2, ws+S_B, ws+S_C, ws+S_S2ACC, N);

  // head
  final_k<<<1, 64, 0, stream>>>(ws, ghist, fc1_w, fc1_b, fc2_w, fc2_b, out);
}

// Round 4
// 892.752 us; speedup vs baseline: 3.7863x; 1.3101x over previous
//
#include <hip/hip_runtime.h>
#include <math.h>

#define N_NODES 10000
#define E_      320000
#define NT2     79                  // ceil(10000/128)
#define NPAD2   (NT2*128)           // 10112
#define PADK    36                  // sim tile row stride (floats)

// ---- workspace layout (float offsets) ----
#define S_CSUM1 0
#define S_CSUM2 32
#define S_GC1   64
#define S_GC2   96
#define S_P1    128
#define S_P2    160
#define S_S1ACC 192
#define S_S2ACC 208
#define S_S0    224
#define S_B1    240               // 512
#define S_C1    752               // 16
#define S_B2    768               // 512
#define S_C2    1280              // 16
#define S_HIST  1296              // 64*16 u32 -> [1296,2320)
#define ZERO_SMALL 2320
#define S_MMSLOT 2320             // 128 u32 (min[64], max[64])
#define S_MM     2448             // 2 u32
#define O_DINV  2560              // 10000 (per-graph, reused)
#define O_INV   12560             // 10000
#define O_OFF   22560             // 10001 ints
#define O_CUR   32564             // 10000 ints
#define O_SRC   42564             // 320000 ints
#define O_BUFH  362564            // N*128
#define O_BUFO  1642564           // N*128
#define O_AF1   2922564           // NPAD2*32 = 323584
#define O_AF2   3246148
// end: 3569732 floats ~= 14.28 MB

__device__ __forceinline__ unsigned f2ord(float f){
  unsigned u = __float_as_uint(f);
  return (u & 0x80000000u) ? ~u : (u | 0x80000000u);
}
__device__ __forceinline__ float ord2f(unsigned u){
  return (u & 0x80000000u) ? __uint_as_float(u & 0x7FFFFFFFu) : __uint_as_float(~u);
}

__global__ void init_k(float* ws){
  int i = blockIdx.x*blockDim.x + threadIdx.x;
  if(i < ZERO_SMALL) ws[i] = 0.f;
  if(i < 128){
    unsigned* sl = (unsigned*)(ws + S_MMSLOT);
    sl[i] = (i < 64) ? 0xFFFFFFFFu : 0u;
  }
  if(i < 2){
    unsigned* mm = (unsigned*)(ws + S_MM);
    mm[i] = (i==0) ? 0xFFFFFFFFu : 0u;
  }
  if(i < (NPAD2 - N_NODES)*32){     // zero af pad rows
    ws[O_AF1 + N_NODES*32 + i] = 0.f;
    ws[O_AF2 + N_NODES*32 + i] = 0.f;
  }
}

__global__ void zero_k(float* p, int n){
  int i = blockIdx.x*blockDim.x + threadIdx.x;
  if(i < n) p[i] = 0.f;
}

__global__ void deg_k(const int* __restrict__ dst, float* __restrict__ degc, int E){
  int i = blockIdx.x*blockDim.x + threadIdx.x;
  if(i < E) atomicAdd(&degc[dst[i]], 1.0f);
}

// single block: exclusive scan of degree counts -> off[n+1], cur[n]; then
// in-place transform dinv = 1/sqrt(deg+1), inv = 1/(deg+1) (disjoint chunks).
__global__ void scan_k(float* __restrict__ dinv, float* __restrict__ inv,
                       int* __restrict__ off, int* __restrict__ cur, int n){
  __shared__ int part[256];
  int t = threadIdx.x;
  int chunk = (n + 255)/256;
  int start = t*chunk, end = min(start+chunk, n);
  int s = 0;
  for(int i=start;i<end;i++) s += (int)dinv[i];
  part[t] = s; __syncthreads();
  if(t==0){
    int run = 0;
    for(int i=0;i<256;i++){ int v=part[i]; part[i]=run; run+=v; }
  }
  __syncthreads();
  int run = part[t];
  for(int i=start;i<end;i++){
    off[i]=run; cur[i]=run; run += (int)dinv[i];
  }
  if(end==n) off[n]=run;
  for(int i=start;i<end;i++){
    float d = dinv[i] + 1.0f;
    dinv[i] = 1.0f/sqrtf(d);
    inv[i]  = 1.0f/d;
  }
}

__global__ void bucket_k(const int* __restrict__ src, const int* __restrict__ dst,
                         int* __restrict__ cur, int* __restrict__ srcs, int E){
  int e = blockIdx.x*blockDim.x + threadIdx.x;
  if(e < E){
    int d = dst[e];
    int pos = atomicAdd(&cur[d], 1);
    srcs[pos] = src[e];
  }
}

// C[n,FOUT] = act(A[n,FIN]) @ W[FIN,FOUT], 4 outputs/thread
template<int FIN, int FOUT, bool RELU>
__global__ __launch_bounds__(256) void gemm_k(const float* __restrict__ A,
                                              const float* __restrict__ W,
                                              float* __restrict__ C, int n){
  constexpr int KC  = (FIN > 64) ? 64 : FIN;
  constexpr int TPR = FOUT/4;              // threads per row
  constexpr int ROWS = 256/TPR;
  __shared__ float4 Ws[KC*TPR];
  int row = blockIdx.x*ROWS + (int)threadIdx.x/TPR;
  int c4  = threadIdx.x % TPR;
  float4 acc = {0.f,0.f,0.f,0.f};
  const float4* W4 = (const float4*)W;
  for(int kc=0; kc<FIN; kc+=KC){
    __syncthreads();
    for(int t=threadIdx.x; t<KC*TPR; t+=256) Ws[t] = W4[(size_t)kc*TPR + t];
    __syncthreads();
    if(row < n){
      const float* a = A + (size_t)row*FIN + kc;
      #pragma unroll
      for(int k=0;k<KC;k++){
        float v = a[k];
        if(RELU) v = fmaxf(v, 0.f);
        float4 w = Ws[k*TPR + c4];
        acc.x = fmaf(v, w.x, acc.x);
        acc.y = fmaf(v, w.y, acc.y);
        acc.z = fmaf(v, w.z, acc.z);
        acc.w = fmaf(v, w.w, acc.w);
      }
    }
  }
  if(row < n) ((float4*)C)[(size_t)row*TPR + c4] = acc;
}

// fused gather-aggregation: out[d] = b + h[d]*inv[d] + sum_{s in N(d)} dinv[s]*dinv[d]*h[s]
template<int F>
__global__ __launch_bounds__(256) void aggr_k(const float* __restrict__ h,
                                              const int* __restrict__ off,
                                              const int* __restrict__ srcs,
                                              const float* __restrict__ dinv,
                                              const float* __restrict__ inv,
                                              const float* __restrict__ bias,
                                              float* __restrict__ out, int n){
  constexpr int G = F/4;
  constexpr int NPB = 256/G;
  int node = blockIdx.x*NPB + (int)threadIdx.x/G;
  int g = threadIdx.x % G;
  if(node >= n) return;
  const float4* h4 = (const float4*)h;
  float4 b4 = ((const float4*)bias)[g];
  float4 hv = h4[(size_t)node*G + g];
  float iv = inv[node];
  float dd = dinv[node];
  float4 acc;
  acc.x = fmaf(hv.x, iv, b4.x);
  acc.y = fmaf(hv.y, iv, b4.y);
  acc.z = fmaf(hv.z, iv, b4.z);
  acc.w = fmaf(hv.w, iv, b4.w);
  int p0 = off[node], p1 = off[node+1];
  for(int base=p0; base<p1; base+=G){
    int idx = base + g;
    int sv = 0; float cv = 0.f;
    if(idx < p1){ sv = srcs[idx]; cv = dinv[sv]*dd; }
    int cnt = min(G, p1-base);
    #pragma unroll 8
    for(int i=0;i<cnt;i++){
      int   si = __shfl(sv, i, G);
      float ci = __shfl(cv, i, G);
      float4 v = h4[(size_t)si*G + g];
      acc.x = fmaf(ci, v.x, acc.x);
      acc.y = fmaf(ci, v.y, acc.y);
      acc.z = fmaf(ci, v.z, acc.z);
      acc.w = fmaf(ci, v.w, acc.w);
    }
  }
  ((float4*)out)[(size_t)node*G + g] = acc;
}

// 128x128 tile, 8x8 microtile, tiles padded to stride 36
template<bool HIST>
__global__ __launch_bounds__(256,3) void sim_k(const float* __restrict__ af1,
                                               const float* __restrict__ af2,
                                               unsigned* __restrict__ mmslot,
                                               const unsigned* __restrict__ mm,
                                               unsigned* __restrict__ ghist){
  __shared__ __align__(16) float ta[128*PADK];
  __shared__ __align__(16) float tb[128*PADK];
  __shared__ unsigned lh[64*17];
  int bx = blockIdx.x % NT2, by = blockIdx.x / NT2;
  int i0 = by*128, j0 = bx*128;
  {
    int row  = threadIdx.x & 127;
    int half = (threadIdx.x >> 7) * 4;
    const float4* A4 = (const float4*)(af1 + (size_t)(i0+row)*32);
    const float4* B4 = (const float4*)(af2 + (size_t)(j0+row)*32);
    float4* tar = (float4*)(ta + row*PADK);
    float4* tbr = (float4*)(tb + row*PADK);
    #pragma unroll
    for(int j=0;j<4;j++){ tar[half+j] = A4[half+j]; tbr[half+j] = B4[half+j]; }
  }
  if(HIST){ for(int t=threadIdx.x; t<64*17; t+=256) lh[t]=0u; }
  __syncthreads();
  int tx = threadIdx.x & 15, ty = threadIdx.x >> 4;
  float acc[8][8];
  #pragma unroll
  for(int r=0;r<8;r++)
    #pragma unroll
    for(int c=0;c<8;c++) acc[r][c]=0.f;
  #pragma unroll 1
  for(int kk=0; kk<32; kk+=4){
    float4 a[8], b[8];
    #pragma unroll
    for(int r=0;r<8;r++) a[r] = *(const float4*)(ta + (ty+16*r)*PADK + kk);
    #pragma unroll
    for(int c=0;c<8;c++) b[c] = *(const float4*)(tb + (tx+16*c)*PADK + kk);
    #pragma unroll
    for(int r=0;r<8;r++){
      #pragma unroll
      for(int c=0;c<8;c++){
        float v = acc[r][c];
        v = fmaf(a[r].x, b[c].x, v);
        v = fmaf(a[r].y, b[c].y, v);
        v = fmaf(a[r].z, b[c].z, v);
        v = fmaf(a[r].w, b[c].w, v);
        acc[r][c] = v;
      }
    }
  }
  bool full = (i0+128 <= N_NODES) && (j0+128 <= N_NODES);
  if(!HIST){
    float m = INFINITY, M = -INFINITY;
    if(full){
      #pragma unroll
      for(int r=0;r<8;r++)
        #pragma unroll
        for(int c=0;c<8;c++){ float v=acc[r][c]; m=fminf(m,v); M=fmaxf(M,v); }
    } else {
      for(int r=0;r<8;r++){
        if(i0+ty+16*r >= N_NODES) continue;
        for(int c=0;c<8;c++){
          if(j0+tx+16*c >= N_NODES) continue;
          float v=acc[r][c]; m=fminf(m,v); M=fmaxf(M,v);
        }
      }
    }
    #pragma unroll
    for(int off=32; off; off>>=1){
      m = fminf(m, __shfl_down(m, off, 64));
      M = fmaxf(M, __shfl_down(M, off, 64));
    }
    if((threadIdx.x & 63)==0){
      int slot = (blockIdx.x*4 + (threadIdx.x>>6)) & 63;
      atomicMin(&mmslot[slot],      f2ord(m));
      atomicMax(&mmslot[64+slot],   f2ord(M));
    }
  } else {
    float lo = ord2f(mm[0]);
    float hi = ord2f(mm[1]);
    float denom = (hi-lo) + 1e-12f;
    unsigned base = (threadIdx.x & 63)*17;
    if(full){
      #pragma unroll
      for(int r=0;r<8;r++)
        #pragma unroll
        for(int c=0;c<8;c++){
          int idx = (int)((acc[r][c]-lo)/denom*16.0f);   // exact reference op order
          idx = idx<0 ? 0 : (idx>15 ? 15 : idx);
          atomicAdd(&lh[base+idx], 1u);
        }
    } else {
      for(int r=0;r<8;r++){
        if(i0+ty+16*r >= N_NODES) continue;
        for(int c=0;c<8;c++){
          if(j0+tx+16*c >= N_NODES) continue;
          int idx = (int)((acc[r][c]-lo)/denom*16.0f);
          idx = idx<0 ? 0 : (idx>15 ? 15 : idx);
          atomicAdd(&lh[base+idx], 1u);
        }
      }
    }
    __syncthreads();
    if(threadIdx.x<16){
      unsigned s=0;
      for(int w=0;w<64;w++) s += lh[w*17+threadIdx.x];
      atomicAdd(&ghist[(blockIdx.x & 63)*16 + threadIdx.x], s);
    }
  }
}

__global__ void mmred_k(float* ws){
  unsigned* sl = (unsigned*)(ws + S_MMSLOT);
  unsigned* mm = (unsigned*)(ws + S_MM);
  int t = threadIdx.x;   // 64 threads
  unsigned mn = sl[t], mx = sl[64+t];
  #pragma unroll
  for(int off=32; off; off>>=1){
    mn = min(mn, (unsigned)__shfl_down((int)mn, off, 64));
    mx = max(mx, (unsigned)__shfl_down((int)mx, off, 64));
  }
  if(t==0){ mm[0]=mn; mm[1]=mx; }
}

// both graphs in one launch: blocks [0,64) -> graph1, [64,128) -> graph2
__global__ void colsum_k(const float* __restrict__ af1, const float* __restrict__ af2,
                         float* __restrict__ csum, int n){
  bool g2 = blockIdx.x >= 64;
  const float* af = g2 ? af2 : af1;
  float* cs = csum + (g2 ? S_CSUM2 - S_CSUM1 : 0);
  int blk = blockIdx.x & 63;
  int f = threadIdx.x % 32;
  int rg = threadIdx.x / 32;
  float acc = 0.f;
  for(int node = blk*8 + rg; node < n; node += 64*8)
    acc += af[(size_t)node*32 + f];
  __shared__ float s[256];
  s[threadIdx.x]=acc; __syncthreads();
  if(threadIdx.x<32){
    float v=0.f;
    for(int r=0;r<8;r++) v += s[r*32+threadIdx.x];
    atomicAdd(&cs[threadIdx.x], v);
  }
}

// both graphs: lanes [0,32) -> graph1, [32,64) -> graph2
__global__ void gc_k(const float* __restrict__ ws_small, const float* __restrict__ att_w,
                     float* __restrict__ gc_base){
  int t = threadIdx.x;
  int j = t & 31;
  const float* csum = ws_small + ((t<32) ? S_CSUM1 : S_CSUM2);
  float* gc = gc_base + ((t<32) ? S_GC1 : S_GC2);
  float acc = 0.f;
  for(int f=0;f<32;f++) acc += csum[f]*att_w[f*32+j];
  gc[j] = tanhf(acc * (1.0f/N_NODES));
}

// both graphs: blocks [0,80) -> graph1, [80,160) -> graph2
__global__ __launch_bounds__(256) void attpool_k(const float* __restrict__ af1,
                                                 const float* __restrict__ af2,
                                                 float* __restrict__ wsmall, int n){
  bool g2 = blockIdx.x >= 80;
  const float* af = g2 ? af2 : af1;
  const float* gc = wsmall + (g2 ? S_GC2 : S_GC1);
  float* p        = wsmall + (g2 ? S_P2  : S_P1);
  int blk = g2 ? blockIdx.x-80 : blockIdx.x;
  __shared__ float sgc[32];
  if(threadIdx.x<32) sgc[threadIdx.x]=gc[threadIdx.x];
  __syncthreads();
  float pacc[32];
  #pragma unroll
  for(int f=0;f<32;f++) pacc[f]=0.f;
  for(int node = blk*256 + threadIdx.x; node < n; node += 80*256){
    const float* row = af + (size_t)node*32;
    float d = 0.f;
    #pragma unroll
    for(int f=0;f<32;f++) d += row[f]*sgc[f];
    float sig = 1.0f/(1.0f+expf(-d));
    #pragma unroll
    for(int f=0;f<32;f++) pacc[f] += row[f]*sig;
  }
  #pragma unroll
  for(int f=0;f<32;f++){
    float v = pacc[f];
    for(int off=32; off; off>>=1) v += __shfl_down(v, off, 64);
    if((threadIdx.x & 63)==0) atomicAdd(&p[f], v);
  }
}

// block0: B1/c1 from p2; block1: B2/c2 from p1; block2: s0 from (p1,p2)
__global__ void bbuild_k(float* __restrict__ wsmall, const float* __restrict__ tn_w,
                         const float* __restrict__ tn_wb, const float* __restrict__ tn_bias){
  int t = threadIdx.x;
  if(blockIdx.x < 2){
    const float* pv = wsmall + (blockIdx.x==0 ? S_P2 : S_P1);
    float* B = wsmall + (blockIdx.x==0 ? S_B1 : S_B2);
    float* c = wsmall + (blockIdx.x==0 ? S_C1 : S_C2);
    if(t < 512){
      int g = t/16, k = t%16;
      float acc = 0.f;
      for(int f=0;f<32;f++) acc += tn_w[(g*32+f)*16+k]*pv[f];
      B[t] = acc + tn_wb[k*64+g];
    }
    if(t < 16){
      float acc = 0.f;
      for(int f=0;f<32;f++) acc += tn_wb[t*64+32+f]*pv[f];
      c[t] = acc + tn_bias[t];
    }
  } else if(t < 16){
    const float* p1 = wsmall + S_P1;
    const float* p2 = wsmall + S_P2;
    float s = 0.f;
    for(int f1=0;f1<32;f1++){
      float a = p1[f1];
      for(int f2=0;f2<32;f2++) s += a*tn_w[(f1*32+f2)*16+t]*p2[f2];
    }
    float blk = 0.f;
    for(int f=0;f<32;f++) blk += tn_wb[t*64+f]*p1[f] + tn_wb[t*64+32+f]*p2[f];
    wsmall[S_S0+t] = fmaxf(s + blk + tn_bias[t], 0.f);
  }
}

// both graphs: blocks [0,80) -> (af1,B1,c1)->S1ACC, [80,160) -> (af2,B2,c2)->S2ACC
__global__ __launch_bounds__(256) void tnmean_k(const float* __restrict__ af1,
                                                const float* __restrict__ af2,
                                                float* __restrict__ wsmall, int n){
  bool g2 = blockIdx.x >= 80;
  const float* X = g2 ? af2 : af1;
  const float* B = wsmall + (g2 ? S_B2 : S_B1);
  const float* c = wsmall + (g2 ? S_C2 : S_C1);
  float* acc_out = wsmall + (g2 ? S_S2ACC : S_S1ACC);
  int blk = g2 ? blockIdx.x-80 : blockIdx.x;
  __shared__ float sB[512];
  __shared__ float sc[16];
  for(int i=threadIdx.x;i<512;i+=256) sB[i]=B[i];
  if(threadIdx.x<16) sc[threadIdx.x]=c[threadIdx.x];
  __syncthreads();
  float a[16];
  #pragma unroll
  for(int k=0;k<16;k++) a[k]=0.f;
  for(int node = blk*256 + threadIdx.x; node < n; node += 80*256){
    const float* row = X + (size_t)node*32;
    float rv[32];
    #pragma unroll
    for(int g=0;g<32;g++) rv[g]=row[g];
    #pragma unroll
    for(int k=0;k<16;k++){
      float y = sc[k];
      #pragma unroll
      for(int g=0;g<32;g++) y += rv[g]*sB[g*16+k];
      a[k] += fmaxf(y, 0.f);
    }
  }
  #pragma unroll
  for(int k=0;k<16;k++){
    float v = a[k];
    for(int off=32; off; off>>=1) v += __shfl_down(v, off, 64);
    if((threadIdx.x & 63)==0) atomicAdd(&acc_out[k], v);
  }
}

// parallel head: 64 threads, 1 block
__global__ void final_k(const float* __restrict__ ws, const unsigned* __restrict__ ghist,
                        const float* __restrict__ fc1_w, const float* __restrict__ fc1_b,
                        const float* __restrict__ fc2_w, const float* __restrict__ fc2_b,
                        float* __restrict__ out){
  __shared__ float sc[64];
  __shared__ float hraw[16];
  __shared__ float sh[16];
  int t = threadIdx.x;
  const float invN = 1.0f/N_NODES;
  if(t<16)      sc[t] = ws[S_S0+t];
  else if(t<32) sc[t] = ws[S_S1ACC+(t-16)]*invN;
  else if(t<48) sc[t] = ws[S_S2ACC+(t-32)]*invN;
  // hist: lane = bin + 16*grp; each grp sums 16 of the 64 slots
  int bin = t & 15, grp = t >> 4;
  unsigned c = 0;
  for(int s=grp; s<64; s+=4) c += ghist[s*16+bin];
  c += (unsigned)__shfl_down((int)c, 32, 64);
  c += (unsigned)__shfl_down((int)c, 16, 64);
  if(t<16){
    float v = (float)c;
    if(v > 16777216.0f) v = 16777216.0f;   // fp32 +1.0 saturation emulation
    hraw[t] = v;
  }
  __syncthreads();
  if(t<16){
    float tot = 0.f;
    for(int b=0;b<16;b++) tot += hraw[b];   // same serial order as reference
    sc[48+t] = hraw[t]/tot;
  }
  __syncthreads();
  if(t<16){
    float a = fc1_b[t];
    for(int i=0;i<64;i++) a += sc[i]*fc1_w[i*16+t];
    sh[t] = fmaxf(a, 0.f);
  }
  __syncthreads();
  if(t==0){
    float o = fc2_b[0];
    for(int j=0;j<16;j++) o += sh[j]*fc2_w[j];
    out[0] = 1.0f/(1.0f+expf(-o));
  }
}

extern "C" void kernel_launch(void* const* d_in, const int* in_sizes, int n_in,
                              void* d_out, int out_size, void* d_ws, size_t ws_size,
                              hipStream_t stream){
  const float* x1      = (const float*)d_in[0];
  const float* x2      = (const float*)d_in[1];
  const int*   ei1     = (const int*)d_in[2];
  const int*   ei2     = (const int*)d_in[3];
  const float* W1      = (const float*)d_in[4];
  const float* b1      = (const float*)d_in[5];
  const float* W2      = (const float*)d_in[6];
  const float* b2      = (const float*)d_in[7];
  const float* W3      = (const float*)d_in[8];
  const float* b3      = (const float*)d_in[9];
  const float* att_w   = (const float*)d_in[10];
  const float* tn_w    = (const float*)d_in[11];
  const float* tn_wb   = (const float*)d_in[12];
  const float* tn_bias = (const float*)d_in[13];
  const float* fc1_w   = (const float*)d_in[14];
  const float* fc1_b   = (const float*)d_in[15];
  const float* fc2_w   = (const float*)d_in[16];
  const float* fc2_b   = (const float*)d_in[17];

  float* ws = (float*)d_ws;
  float* out = (float*)d_out;
  const int N = N_NODES, E = E_;

  unsigned* mmslot = (unsigned*)(ws + S_MMSLOT);
  unsigned* mm     = (unsigned*)(ws + S_MM);
  unsigned* ghist  = (unsigned*)(ws + S_HIST);
  int* off  = (int*)(ws + O_OFF);
  int* cur  = (int*)(ws + O_CUR);
  int* srcs = (int*)(ws + O_SRC);

  init_k<<<((NPAD2-N_NODES)*32+255)/256, 256, 0, stream>>>(ws);

  for(int g=0; g<2; g++){
    const float* x = g ? x2 : x1;
    const int* src = (g ? ei2 : ei1);
    const int* dst = src + E;
    float* dinv = ws + O_DINV;
    float* inv  = ws + O_INV;
    float* af   = ws + (g ? O_AF2 : O_AF1);
    float* bufH = ws + O_BUFH;
    float* bufO = ws + O_BUFO;

    // CSR build (reused for 3 layers)
    zero_k<<<(N+255)/256, 256, 0, stream>>>(dinv, N);
    deg_k<<<(E+255)/256, 256, 0, stream>>>(dst, dinv, E);
    scan_k<<<1, 256, 0, stream>>>(dinv, inv, off, cur, N);
    bucket_k<<<(E+255)/256, 256, 0, stream>>>(src, dst, cur, srcs, E);

    // layer 1: 128 -> 128
    gemm_k<128,128,false><<<(N+7)/8, 256, 0, stream>>>(x, W1, bufH, N);
    aggr_k<128><<<(N+7)/8, 256, 0, stream>>>(bufH, off, srcs, dinv, inv, b1, bufO, N);
    // layer 2: 128 -> 64
    gemm_k<128,64,true><<<(N+15)/16, 256, 0, stream>>>(bufO, W2, bufH, N);
    aggr_k<64><<<(N+15)/16, 256, 0, stream>>>(bufH, off, srcs, dinv, inv, b2, bufO, N);
    // layer 3: 64 -> 32
    gemm_k<64,32,true><<<(N+31)/32, 256, 0, stream>>>(bufO, W3, bufH, N);
    aggr_k<32><<<(N+31)/32, 256, 0, stream>>>(bufH, off, srcs, dinv, inv, b3, af, N);
  }

  // similarity: min/max pass -> slot reduce -> histogram pass
  sim_k<false><<<NT2*NT2, 256, 0, stream>>>(ws+O_AF1, ws+O_AF2, mmslot, mm, ghist);
  mmred_k<<<1, 64, 0, stream>>>(ws);
  sim_k<true ><<<NT2*NT2, 256, 0, stream>>>(ws+O_AF1, ws+O_AF2, mmslot, mm, ghist);

  // attention pooling (both graphs per launch)
  colsum_k<<<128, 256, 0, stream>>>(ws+O_AF1, ws+O_AF2, ws+S_CSUM1, N);
  gc_k<<<1, 64, 0, stream>>>(ws, att_w, ws);
  attpool_k<<<160, 256, 0, stream>>>(ws+O_AF1, ws+O_AF2, ws, N);

  // tensor-network scores
  bbuild_k<<<3, 512, 0, stream>>>(ws, tn_w, tn_wb, tn_bias);
  tnmean_k<<<160, 256, 0, stream>>>(ws+O_AF1, ws+O_AF2, ws, N);

  // head
  final_k<<<1, 64, 0, stream>>>(ws, ghist, fc1_w, fc1_b, fc2_w, fc2_b, out);
}

// Round 5
// 857.903 us; speedup vs baseline: 3.9401x; 1.0406x over previous
//
#include <hip/hip_runtime.h>
#include <math.h>

#define N_NODES 10000
#define E_      320000
#define NT2     79                  // ceil(10000/128)
#define NPAD2   (NT2*128)           // 10112
#define PADK    36                  // sim tile row stride (floats)

// ---- small workspace area (float offsets), same in both layouts ----
#define S_CSUM1 0
#define S_CSUM2 32
#define S_GC1   64
#define S_GC2   96
#define S_P1    128
#define S_P2    160
#define S_S1ACC 192
#define S_S2ACC 208
#define S_S0    224
#define S_B1    240               // 512
#define S_C1    752               // 16
#define S_B2    768               // 512
#define S_C2    1280              // 16
#define S_HIST  1296              // 64*16 u32 -> [1296,2320)
#define ZERO_SMALL 2320
#define S_MMSLOT 2320             // 128 u32 (min[64], max[64])
#define S_MM     2448             // 2 u32
#define SMALL_END 2560

#define WS_BIG_END 7129736ull     // floats (~28.5 MB)

__device__ __forceinline__ unsigned f2ord(float f){
  unsigned u = __float_as_uint(f);
  return (u & 0x80000000u) ? ~u : (u | 0x80000000u);
}
__device__ __forceinline__ float ord2f(unsigned u){
  return (u & 0x80000000u) ? __uint_as_float(u & 0x7FFFFFFFu) : __uint_as_float(~u);
}

__global__ void init_k(float* ws, float* dvA, float* dvB, float* af1, float* af2){
  int i = blockIdx.x*blockDim.x + threadIdx.x;   // grid covers [0,10000)
  if(i < ZERO_SMALL) ws[i] = 0.f;
  if(i < 128){
    unsigned* sl = (unsigned*)(ws + S_MMSLOT);
    sl[i] = (i < 64) ? 0xFFFFFFFFu : 0u;
  }
  if(i < 2){
    unsigned* mm = (unsigned*)(ws + S_MM);
    mm[i] = (i==0) ? 0xFFFFFFFFu : 0u;
  }
  if(i < N_NODES){ dvA[i] = 0.f; dvB[i] = 0.f; }
  if(i < (NPAD2 - N_NODES)*32){     // zero af pad rows
    af1[N_NODES*32 + i] = 0.f;
    af2[N_NODES*32 + i] = 0.f;
  }
}

__global__ void zero_k(float* p, int n){
  int i = blockIdx.x*blockDim.x + threadIdx.x;
  if(i < n) p[i] = 0.f;
}

// degree count for up to two graphs in one launch: i<E -> A, else B
__global__ void deg_k(const int* __restrict__ dstA, const int* __restrict__ dstB,
                      float* __restrict__ degA, float* __restrict__ degB,
                      int E, int nTot){
  int i = blockIdx.x*blockDim.x + threadIdx.x;
  if(i >= nTot) return;
  bool b = i >= E;
  const int* dst = b ? dstB : dstA;
  float* deg     = b ? degB : degA;
  atomicAdd(&deg[dst[b ? i-E : i]], 1.0f);
}

// block b scans graph b: exclusive scan -> off[n+1], cur[n]; then dinv/inv transform
__global__ void scan_k(float* dv0, float* iv0, int* of0, int* cu0,
                       float* dv1, float* iv1, int* of1, int* cu1, int n){
  float* dinv = blockIdx.x ? dv1 : dv0;
  float* inv  = blockIdx.x ? iv1 : iv0;
  int* off    = blockIdx.x ? of1 : of0;
  int* cur    = blockIdx.x ? cu1 : cu0;
  __shared__ int part[256];
  int t = threadIdx.x;
  int chunk = (n + 255)/256;
  int start = t*chunk, end = min(start+chunk, n);
  int s = 0;
  for(int i=start;i<end;i++) s += (int)dinv[i];
  part[t] = s; __syncthreads();
  if(t==0){
    int run = 0;
    for(int i=0;i<256;i++){ int v=part[i]; part[i]=run; run+=v; }
  }
  __syncthreads();
  int run = part[t];
  for(int i=start;i<end;i++){
    off[i]=run; cur[i]=run; run += (int)dinv[i];
  }
  if(end==n) off[n]=run;
  for(int i=start;i<end;i++){
    float d = dinv[i] + 1.0f;
    dinv[i] = 1.0f/sqrtf(d);
    inv[i]  = 1.0f/d;
  }
}

// bucket edges into CSR, storing src AND precomputed coef = dinv[s]*dinv[d]
__global__ void bucket_k(const int* __restrict__ eA, const int* __restrict__ eB,
                         int* curA, int* curB,
                         const float* __restrict__ dvA, const float* __restrict__ dvB,
                         int* __restrict__ srA, int* __restrict__ srB,
                         float* __restrict__ cfA, float* __restrict__ cfB,
                         int E, int nTot){
  int i = blockIdx.x*blockDim.x + threadIdx.x;
  if(i >= nTot) return;
  bool b = i >= E;
  int e = b ? i-E : i;
  const int* ei = b ? eB : eA;
  int* cur = b ? curB : curA;
  const float* dv = b ? dvB : dvA;
  int* ss = b ? srB : srA;
  float* cc = b ? cfB : cfA;
  int s = ei[e], d = ei[E+e];
  int pos = atomicAdd(&cur[d], 1);
  ss[pos] = s;
  cc[pos] = dv[s]*dv[d];
}

// C[n,FOUT] = act(A[n,FIN]) @ W[FIN,FOUT], 4 outputs/thread, dual-graph
template<int FIN, int FOUT, bool RELU>
__global__ __launch_bounds__(256) void gemm_k(const float* __restrict__ A0,
                                              const float* __restrict__ A1,
                                              const float* __restrict__ W,
                                              float* __restrict__ C0,
                                              float* __restrict__ C1,
                                              int n, int bpg){
  constexpr int KC  = (FIN > 64) ? 64 : FIN;
  constexpr int TPR = FOUT/4;
  constexpr int ROWS = 256/TPR;
  __shared__ float4 Ws[KC*TPR];
  bool gsel = blockIdx.x >= bpg;
  int blk = gsel ? blockIdx.x - bpg : blockIdx.x;
  const float* A = gsel ? A1 : A0;
  float* C       = gsel ? C1 : C0;
  int row = blk*ROWS + (int)threadIdx.x/TPR;
  int c4  = threadIdx.x % TPR;
  float4 acc = {0.f,0.f,0.f,0.f};
  const float4* W4 = (const float4*)W;
  for(int kc=0; kc<FIN; kc+=KC){
    __syncthreads();
    for(int t=threadIdx.x; t<KC*TPR; t+=256) Ws[t] = W4[(size_t)kc*TPR + t];
    __syncthreads();
    if(row < n){
      const float* a = A + (size_t)row*FIN + kc;
      #pragma unroll
      for(int k=0;k<KC;k++){
        float v = a[k];
        if(RELU) v = fmaxf(v, 0.f);
        float4 w = Ws[k*TPR + c4];
        acc.x = fmaf(v, w.x, acc.x);
        acc.y = fmaf(v, w.y, acc.y);
        acc.z = fmaf(v, w.z, acc.z);
        acc.w = fmaf(v, w.w, acc.w);
      }
    }
  }
  if(row < n) ((float4*)C)[(size_t)row*TPR + c4] = acc;
}

// fused gather-aggregation: out[d] = b + h[d]*inv[d] + sum coefs[p]*h[srcs[p]]
// dual-graph; (src,coef) loads are subgroup-uniform (broadcast), 4 in flight
template<int F>
__global__ __launch_bounds__(256) void aggr_k(const float* __restrict__ h0,
                                              const float* __restrict__ h1,
                                              const int* __restrict__ of0,
                                              const int* __restrict__ of1,
                                              const int* __restrict__ sr0,
                                              const int* __restrict__ sr1,
                                              const float* __restrict__ cf0,
                                              const float* __restrict__ cf1,
                                              const float* __restrict__ iv0,
                                              const float* __restrict__ iv1,
                                              const float* __restrict__ bias,
                                              float* __restrict__ o0,
                                              float* __restrict__ o1,
                                              int n, int bpg){
  constexpr int G = F/4;
  constexpr int NPB = 256/G;
  bool gsel = blockIdx.x >= bpg;
  int blk = gsel ? blockIdx.x - bpg : blockIdx.x;
  const float* h = gsel ? h1 : h0;
  const int* off = gsel ? of1 : of0;
  const int* srcs = gsel ? sr1 : sr0;
  const float* cf = gsel ? cf1 : cf0;
  const float* inv = gsel ? iv1 : iv0;
  float* out = gsel ? o1 : o0;
  int node = blk*NPB + (int)threadIdx.x/G;
  int g = threadIdx.x % G;
  if(node >= n) return;
  const float4* h4 = (const float4*)h;
  float4 b4 = ((const float4*)bias)[g];
  float4 hv = h4[(size_t)node*G + g];
  float iv = inv[node];
  float4 acc;
  acc.x = fmaf(hv.x, iv, b4.x);
  acc.y = fmaf(hv.y, iv, b4.y);
  acc.z = fmaf(hv.z, iv, b4.z);
  acc.w = fmaf(hv.w, iv, b4.w);
  int p = off[node], p1 = off[node+1];
  for(; p+4<=p1; p+=4){
    int s0=srcs[p], s1=srcs[p+1], s2=srcs[p+2], s3=srcs[p+3];
    float c0=cf[p], c1=cf[p+1], c2=cf[p+2], c3=cf[p+3];
    float4 v0=h4[(size_t)s0*G+g], v1=h4[(size_t)s1*G+g];
    float4 v2=h4[(size_t)s2*G+g], v3=h4[(size_t)s3*G+g];
    acc.x=fmaf(c0,v0.x,acc.x); acc.y=fmaf(c0,v0.y,acc.y); acc.z=fmaf(c0,v0.z,acc.z); acc.w=fmaf(c0,v0.w,acc.w);
    acc.x=fmaf(c1,v1.x,acc.x); acc.y=fmaf(c1,v1.y,acc.y); acc.z=fmaf(c1,v1.z,acc.z); acc.w=fmaf(c1,v1.w,acc.w);
    acc.x=fmaf(c2,v2.x,acc.x); acc.y=fmaf(c2,v2.y,acc.y); acc.z=fmaf(c2,v2.z,acc.z); acc.w=fmaf(c2,v2.w,acc.w);
    acc.x=fmaf(c3,v3.x,acc.x); acc.y=fmaf(c3,v3.y,acc.y); acc.z=fmaf(c3,v3.z,acc.z); acc.w=fmaf(c3,v3.w,acc.w);
  }
  for(; p<p1; ++p){
    int s = srcs[p];
    float c = cf[p];
    float4 v = h4[(size_t)s*G + g];
    acc.x=fmaf(c,v.x,acc.x); acc.y=fmaf(c,v.y,acc.y);
    acc.z=fmaf(c,v.z,acc.z); acc.w=fmaf(c,v.w,acc.w);
  }
  ((float4*)out)[(size_t)node*G + g] = acc;
}

__device__ __forceinline__ void ld_frag(const float* pa, const float* pb, int kk,
                                        float4* a, float4* b){
  #pragma unroll
  for(int r=0;r<8;r++) a[r] = *(const float4*)(pa + r*16*PADK + kk);
  #pragma unroll
  for(int c=0;c<8;c++) b[c] = *(const float4*)(pb + c*16*PADK + kk);
}
__device__ __forceinline__ void fma_frag(float acc[8][8], const float4* a, const float4* b){
  #pragma unroll
  for(int r=0;r<8;r++){
    #pragma unroll
    for(int c=0;c<8;c++){
      float v = acc[r][c];
      v = fmaf(a[r].x, b[c].x, v);
      v = fmaf(a[r].y, b[c].y, v);
      v = fmaf(a[r].z, b[c].z, v);
      v = fmaf(a[r].w, b[c].w, v);
      acc[r][c] = v;
    }
  }
}

// 128x128 tile, 8x8 microtile, stride-36 tiles, software-pipelined k-loop
template<bool HIST>
__global__ __launch_bounds__(256,2) void sim_k(const float* __restrict__ af1,
                                               const float* __restrict__ af2,
                                               unsigned* __restrict__ mmslot,
                                               const unsigned* __restrict__ mm,
                                               unsigned* __restrict__ ghist){
  __shared__ __align__(16) float ta[128*PADK];
  __shared__ __align__(16) float tb[128*PADK];
  __shared__ unsigned lh[64*17];
  int bx = blockIdx.x % NT2, by = blockIdx.x / NT2;
  int i0 = by*128, j0 = bx*128;
  {
    int row  = threadIdx.x & 127;
    int half = (threadIdx.x >> 7) * 4;
    const float4* A4 = (const float4*)(af1 + (size_t)(i0+row)*32);
    const float4* B4 = (const float4*)(af2 + (size_t)(j0+row)*32);
    float4* tar = (float4*)(ta + row*PADK);
    float4* tbr = (float4*)(tb + row*PADK);
    #pragma unroll
    for(int j=0;j<4;j++){ tar[half+j] = A4[half+j]; tbr[half+j] = B4[half+j]; }
  }
  if(HIST){ for(int t=threadIdx.x; t<64*17; t+=256) lh[t]=0u; }
  __syncthreads();
  int tx = threadIdx.x & 15, ty = threadIdx.x >> 4;
  const float* pa = ta + ty*PADK;
  const float* pb = tb + tx*PADK;
  float acc[8][8];
  #pragma unroll
  for(int r=0;r<8;r++)
    #pragma unroll
    for(int c=0;c<8;c++) acc[r][c]=0.f;
  float4 a0[8], b0[8], a1[8], b1[8];
  ld_frag(pa, pb, 0, a0, b0);
  #pragma unroll 1
  for(int kk=0; kk<24; kk+=8){
    ld_frag(pa, pb, kk+4, a1, b1);
    fma_frag(acc, a0, b0);
    ld_frag(pa, pb, kk+8, a0, b0);
    fma_frag(acc, a1, b1);
  }
  ld_frag(pa, pb, 28, a1, b1);
  fma_frag(acc, a0, b0);
  fma_frag(acc, a1, b1);

  bool full = (i0+128 <= N_NODES) && (j0+128 <= N_NODES);
  if(!HIST){
    float m = INFINITY, M = -INFINITY;
    if(full){
      #pragma unroll
      for(int r=0;r<8;r++)
        #pragma unroll
        for(int c=0;c<8;c++){ float v=acc[r][c]; m=fminf(m,v); M=fmaxf(M,v); }
    } else {
      for(int r=0;r<8;r++){
        if(i0+ty+16*r >= N_NODES) continue;
        for(int c=0;c<8;c++){
          if(j0+tx+16*c >= N_NODES) continue;
          float v=acc[r][c]; m=fminf(m,v); M=fmaxf(M,v);
        }
      }
    }
    #pragma unroll
    for(int off=32; off; off>>=1){
      m = fminf(m, __shfl_down(m, off, 64));
      M = fmaxf(M, __shfl_down(M, off, 64));
    }
    if((threadIdx.x & 63)==0){
      int slot = (blockIdx.x*4 + (threadIdx.x>>6)) & 63;
      atomicMin(&mmslot[slot],    f2ord(m));
      atomicMax(&mmslot[64+slot], f2ord(M));
    }
  } else {
    float lo = ord2f(mm[0]);
    float hi = ord2f(mm[1]);
    float denom = (hi-lo) + 1e-12f;
    unsigned base = (threadIdx.x & 63)*17;
    if(full){
      #pragma unroll
      for(int r=0;r<8;r++)
        #pragma unroll
        for(int c=0;c<8;c++){
          int idx = (int)((acc[r][c]-lo)/denom*16.0f);   // exact reference op order
          idx = idx<0 ? 0 : (idx>15 ? 15 : idx);
          atomicAdd(&lh[base+idx], 1u);
        }
    } else {
      for(int r=0;r<8;r++){
        if(i0+ty+16*r >= N_NODES) continue;
        for(int c=0;c<8;c++){
          if(j0+tx+16*c >= N_NODES) continue;
          int idx = (int)((acc[r][c]-lo)/denom*16.0f);
          idx = idx<0 ? 0 : (idx>15 ? 15 : idx);
          atomicAdd(&lh[base+idx], 1u);
        }
      }
    }
    __syncthreads();
    if(threadIdx.x<16){
      unsigned s=0;
      for(int w=0;w<64;w++) s += lh[w*17+threadIdx.x];
      atomicAdd(&ghist[(blockIdx.x & 63)*16 + threadIdx.x], s);
    }
  }
}

__global__ void mmred_k(float* ws){
  unsigned* sl = (unsigned*)(ws + S_MMSLOT);
  unsigned* mm = (unsigned*)(ws + S_MM);
  int t = threadIdx.x;   // 64 threads
  unsigned mn = sl[t], mx = sl[64+t];
  #pragma unroll
  for(int off=32; off; off>>=1){
    mn = min(mn, (unsigned)__shfl_down((int)mn, off, 64));
    mx = max(mx, (unsigned)__shfl_down((int)mx, off, 64));
  }
  if(t==0){ mm[0]=mn; mm[1]=mx; }
}

// blocks [0,64) -> graph1, [64,128) -> graph2
__global__ void colsum_k(const float* __restrict__ af1, const float* __restrict__ af2,
                         float* __restrict__ csum, int n){
  bool g2 = blockIdx.x >= 64;
  const float* af = g2 ? af2 : af1;
  float* cs = csum + (g2 ? S_CSUM2 - S_CSUM1 : 0);
  int blk = blockIdx.x & 63;
  int f = threadIdx.x % 32;
  int rg = threadIdx.x / 32;
  float acc = 0.f;
  for(int node = blk*8 + rg; node < n; node += 64*8)
    acc += af[(size_t)node*32 + f];
  __shared__ float s[256];
  s[threadIdx.x]=acc; __syncthreads();
  if(threadIdx.x<32){
    float v=0.f;
    for(int r=0;r<8;r++) v += s[r*32+threadIdx.x];
    atomicAdd(&cs[threadIdx.x], v);
  }
}

// lanes [0,32) -> graph1, [32,64) -> graph2
__global__ void gc_k(const float* __restrict__ ws_small, const float* __restrict__ att_w,
                     float* __restrict__ gc_base){
  int t = threadIdx.x;
  int j = t & 31;
  const float* csum = ws_small + ((t<32) ? S_CSUM1 : S_CSUM2);
  float* gc = gc_base + ((t<32) ? S_GC1 : S_GC2);
  float acc = 0.f;
  for(int f=0;f<32;f++) acc += csum[f]*att_w[f*32+j];
  gc[j] = tanhf(acc * (1.0f/N_NODES));
}

// blocks [0,80) -> graph1, [80,160) -> graph2
__global__ __launch_bounds__(256) void attpool_k(const float* __restrict__ af1,
                                                 const float* __restrict__ af2,
                                                 float* __restrict__ wsmall, int n){
  bool g2 = blockIdx.x >= 80;
  const float* af = g2 ? af2 : af1;
  const float* gc = wsmall + (g2 ? S_GC2 : S_GC1);
  float* p        = wsmall + (g2 ? S_P2  : S_P1);
  int blk = g2 ? blockIdx.x-80 : blockIdx.x;
  __shared__ float sgc[32];
  if(threadIdx.x<32) sgc[threadIdx.x]=gc[threadIdx.x];
  __syncthreads();
  float pacc[32];
  #pragma unroll
  for(int f=0;f<32;f++) pacc[f]=0.f;
  for(int node = blk*256 + threadIdx.x; node < n; node += 80*256){
    const float* row = af + (size_t)node*32;
    float d = 0.f;
    #pragma unroll
    for(int f=0;f<32;f++) d += row[f]*sgc[f];
    float sig = 1.0f/(1.0f+expf(-d));
    #pragma unroll
    for(int f=0;f<32;f++) pacc[f] += row[f]*sig;
  }
  #pragma unroll
  for(int f=0;f<32;f++){
    float v = pacc[f];
    for(int off=32; off; off>>=1) v += __shfl_down(v, off, 64);
    if((threadIdx.x & 63)==0) atomicAdd(&p[f], v);
  }
}

// block0: B1/c1 from p2; block1: B2/c2 from p1; block2: s0 from (p1,p2)
__global__ void bbuild_k(float* __restrict__ wsmall, const float* __restrict__ tn_w,
                         const float* __restrict__ tn_wb, const float* __restrict__ tn_bias){
  int t = threadIdx.x;
  if(blockIdx.x < 2){
    const float* pv = wsmall + (blockIdx.x==0 ? S_P2 : S_P1);
    float* B = wsmall + (blockIdx.x==0 ? S_B1 : S_B2);
    float* c = wsmall + (blockIdx.x==0 ? S_C1 : S_C2);
    if(t < 512){
      int g = t/16, k = t%16;
      float acc = 0.f;
      for(int f=0;f<32;f++) acc += tn_w[(g*32+f)*16+k]*pv[f];
      B[t] = acc + tn_wb[k*64+g];
    }
    if(t < 16){
      float acc = 0.f;
      for(int f=0;f<32;f++) acc += tn_wb[t*64+32+f]*pv[f];
      c[t] = acc + tn_bias[t];
    }
  } else if(t < 16){
    const float* p1 = wsmall + S_P1;
    const float* p2 = wsmall + S_P2;
    float s = 0.f;
    for(int f1=0;f1<32;f1++){
      float a = p1[f1];
      for(int f2=0;f2<32;f2++) s += a*tn_w[(f1*32+f2)*16+t]*p2[f2];
    }
    float blk = 0.f;
    for(int f=0;f<32;f++) blk += tn_wb[t*64+f]*p1[f] + tn_wb[t*64+32+f]*p2[f];
    wsmall[S_S0+t] = fmaxf(s + blk + tn_bias[t], 0.f);
  }
}

// blocks [0,80) -> (af1,B1,c1)->S1ACC, [80,160) -> (af2,B2,c2)->S2ACC
__global__ __launch_bounds__(256) void tnmean_k(const float* __restrict__ af1,
                                                const float* __restrict__ af2,
                                                float* __restrict__ wsmall, int n){
  bool g2 = blockIdx.x >= 80;
  const float* X = g2 ? af2 : af1;
  const float* B = wsmall + (g2 ? S_B2 : S_B1);
  const float* c = wsmall + (g2 ? S_C2 : S_C1);
  float* acc_out = wsmall + (g2 ? S_S2ACC : S_S1ACC);
  int blk = g2 ? blockIdx.x-80 : blockIdx.x;
  __shared__ float sB[512];
  __shared__ float sc[16];
  for(int i=threadIdx.x;i<512;i+=256) sB[i]=B[i];
  if(threadIdx.x<16) sc[threadIdx.x]=c[threadIdx.x];
  __syncthreads();
  float a[16];
  #pragma unroll
  for(int k=0;k<16;k++) a[k]=0.f;
  for(int node = blk*256 + threadIdx.x; node < n; node += 80*256){
    const float* row = X + (size_t)node*32;
    float rv[32];
    #pragma unroll
    for(int g=0;g<32;g++) rv[g]=row[g];
    #pragma unroll
    for(int k=0;k<16;k++){
      float y = sc[k];
      #pragma unroll
      for(int g=0;g<32;g++) y += rv[g]*sB[g*16+k];
      a[k] += fmaxf(y, 0.f);
    }
  }
  #pragma unroll
  for(int k=0;k<16;k++){
    float v = a[k];
    for(int off=32; off; off>>=1) v += __shfl_down(v, off, 64);
    if((threadIdx.x & 63)==0) atomicAdd(&acc_out[k], v);
  }
}

// parallel head: 64 threads, 1 block
__global__ void final_k(const float* __restrict__ ws, const unsigned* __restrict__ ghist,
                        const float* __restrict__ fc1_w, const float* __restrict__ fc1_b,
                        const float* __restrict__ fc2_w, const float* __restrict__ fc2_b,
                        float* __restrict__ out){
  __shared__ float sc[64];
  __shared__ float hraw[16];
  __shared__ float sh[16];
  int t = threadIdx.x;
  const float invN = 1.0f/N_NODES;
  if(t<16)      sc[t] = ws[S_S0+t];
  else if(t<32) sc[t] = ws[S_S1ACC+(t-16)]*invN;
  else if(t<48) sc[t] = ws[S_S2ACC+(t-32)]*invN;
  int bin = t & 15, grp = t >> 4;
  unsigned c = 0;
  for(int s=grp; s<64; s+=4) c += ghist[s*16+bin];
  c += (unsigned)__shfl_down((int)c, 32, 64);
  c += (unsigned)__shfl_down((int)c, 16, 64);
  if(t<16){
    float v = (float)c;
    if(v > 16777216.0f) v = 16777216.0f;   // fp32 +1.0 saturation emulation
    hraw[t] = v;
  }
  __syncthreads();
  if(t<16){
    float tot = 0.f;
    for(int b=0;b<16;b++) tot += hraw[b];   // same serial order as reference
    sc[48+t] = hraw[t]/tot;
  }
  __syncthreads();
  if(t<16){
    float a = fc1_b[t];
    for(int i=0;i<64;i++) a += sc[i]*fc1_w[i*16+t];
    sh[t] = fmaxf(a, 0.f);
  }
  __syncthreads();
  if(t==0){
    float o = fc2_b[0];
    for(int j=0;j<16;j++) o += sh[j]*fc2_w[j];
    out[0] = 1.0f/(1.0f+expf(-o));
  }
}

extern "C" void kernel_launch(void* const* d_in, const int* in_sizes, int n_in,
                              void* d_out, int out_size, void* d_ws, size_t ws_size,
                              hipStream_t stream){
  const float* x1      = (const float*)d_in[0];
  const float* x2      = (const float*)d_in[1];
  const int*   ei1     = (const int*)d_in[2];
  const int*   ei2     = (const int*)d_in[3];
  const float* W1      = (const float*)d_in[4];
  const float* b1      = (const float*)d_in[5];
  const float* W2      = (const float*)d_in[6];
  const float* b2      = (const float*)d_in[7];
  const float* W3      = (const float*)d_in[8];
  const float* b3      = (const float*)d_in[9];
  const float* att_w   = (const float*)d_in[10];
  const float* tn_w    = (const float*)d_in[11];
  const float* tn_wb   = (const float*)d_in[12];
  const float* tn_bias = (const float*)d_in[13];
  const float* fc1_w   = (const float*)d_in[14];
  const float* fc1_b   = (const float*)d_in[15];
  const float* fc2_w   = (const float*)d_in[16];
  const float* fc2_b   = (const float*)d_in[17];

  float* ws = (float*)d_ws;
  float* out = (float*)d_out;
  const int N = N_NODES, E = E_;

  bool big = ws_size >= WS_BIG_END*sizeof(float);

  // layout (float offsets); small mode overlays graph-2 scratch on graph-1
  size_t oDV1, oDV2, oIV1, oIV2, oOF1, oOF2, oCU1, oCU2, oSR1, oSR2,
         oCF1, oCF2, oBH1, oBH2, oBO1, oBO2, oAF1, oAF2;
  if(big){
    oDV1=2560;    oDV2=12560;   oIV1=22560;   oIV2=32560;
    oOF1=42560;   oOF2=52564;   oCU1=62568;   oCU2=72568;
    oSR1=82568;   oSR2=402568;  oCF1=722568;  oCF2=1042568;
    oBH1=1362568; oBH2=2642568; oBO1=3922568; oBO2=5202568;
    oAF1=6482568; oAF2=6806152;
  } else {
    oDV1=2560;    oDV2=oDV1;    oIV1=12560;   oIV2=oIV1;
    oOF1=22560;   oOF2=oOF1;    oCU1=32564;   oCU2=oCU1;
    oSR1=42564;   oSR2=oSR1;    oCF1=362564;  oCF2=oCF1;
    oBH1=682564;  oBH2=oBH1;    oBO1=1962564; oBO2=oBO1;
    oAF1=3242564; oAF2=3566148;
  }
  float* dv1=ws+oDV1; float* dv2=ws+oDV2;
  float* iv1=ws+oIV1; float* iv2=ws+oIV2;
  int* of1=(int*)(ws+oOF1); int* of2=(int*)(ws+oOF2);
  int* cu1=(int*)(ws+oCU1); int* cu2=(int*)(ws+oCU2);
  int* sr1=(int*)(ws+oSR1); int* sr2=(int*)(ws+oSR2);
  float* cf1=ws+oCF1; float* cf2=ws+oCF2;
  float* bh1=ws+oBH1; float* bh2=ws+oBH2;
  float* bo1=ws+oBO1; float* bo2=ws+oBO2;
  float* af1=ws+oAF1; float* af2=ws+oAF2;

  unsigned* mmslot = (unsigned*)(ws + S_MMSLOT);
  unsigned* mm     = (unsigned*)(ws + S_MM);
  unsigned* ghist  = (unsigned*)(ws + S_HIST);

  const int BPG1 = (N+7)/8,  BPA1 = (N+1)/2;    // gemm/aggr F=128
  const int BPG2 = (N+15)/16, BPA2 = (N+3)/4;   // F=64
  const int BPG3 = (N+31)/32, BPA3 = (N+7)/8;   // F=32

  init_k<<<(N+255)/256, 256, 0, stream>>>(ws, dv1, dv2, af1, af2);

  if(big){
    deg_k<<<(2*E+255)/256, 256, 0, stream>>>(ei1+E, ei2+E, dv1, dv2, E, 2*E);
    scan_k<<<2, 256, 0, stream>>>(dv1, iv1, of1, cu1, dv2, iv2, of2, cu2, N);
    bucket_k<<<(2*E+255)/256, 256, 0, stream>>>(ei1, ei2, cu1, cu2, dv1, dv2,
                                                sr1, sr2, cf1, cf2, E, 2*E);
    gemm_k<128,128,false><<<2*BPG1, 256, 0, stream>>>(x1, x2, W1, bh1, bh2, N, BPG1);
    aggr_k<128><<<2*BPA1, 256, 0, stream>>>(bh1,bh2, of1,of2, sr1,sr2, cf1,cf2,
                                            iv1,iv2, b1, bo1,bo2, N, BPA1);
    gemm_k<128,64,true><<<2*BPG2, 256, 0, stream>>>(bo1, bo2, W2, bh1, bh2, N, BPG2);
    aggr_k<64><<<2*BPA2, 256, 0, stream>>>(bh1,bh2, of1,of2, sr1,sr2, cf1,cf2,
                                           iv1,iv2, b2, bo1,bo2, N, BPA2);
    gemm_k<64,32,true><<<2*BPG3, 256, 0, stream>>>(bo1, bo2, W3, bh1, bh2, N, BPG3);
    aggr_k<32><<<2*BPA3, 256, 0, stream>>>(bh1,bh2, of1,of2, sr1,sr2, cf1,cf2,
                                           iv1,iv2, b3, af1,af2, N, BPA3);
  } else {
    for(int g=0; g<2; g++){
      const float* x = g ? x2 : x1;
      const int* ei  = g ? ei2 : ei1;
      float* af      = g ? af2 : af1;
      if(g) zero_k<<<(N+255)/256, 256, 0, stream>>>(dv1, N);
      deg_k<<<(E+255)/256, 256, 0, stream>>>(ei+E, ei+E, dv1, dv1, E, E);
      scan_k<<<1, 256, 0, stream>>>(dv1, iv1, of1, cu1, dv1, iv1, of1, cu1, N);
      bucket_k<<<(E+255)/256, 256, 0, stream>>>(ei, ei, cu1, cu1, dv1, dv1,
                                                sr1, sr1, cf1, cf1, E, E);
      gemm_k<128,128,false><<<BPG1, 256, 0, stream>>>(x, x, W1, bh1, bh1, N, BPG1);
      aggr_k<128><<<BPA1, 256, 0, stream>>>(bh1,bh1, of1,of1, sr1,sr1, cf1,cf1,
                                            iv1,iv1, b1, bo1,bo1, N, BPA1);
      gemm_k<128,64,true><<<BPG2, 256, 0, stream>>>(bo1, bo1, W2, bh1, bh1, N, BPG2);
      aggr_k<64><<<BPA2, 256, 0, stream>>>(bh1,bh1, of1,of1, sr1,sr1, cf1,cf1,
                                           iv1,iv1, b2, bo1,bo1, N, BPA2);
      gemm_k<64,32,true><<<BPG3, 256, 0, stream>>>(bo1, bo1, W3, bh1, bh1, N, BPG3);
      aggr_k<32><<<BPA3, 256, 0, stream>>>(bh1,bh1, of1,of1, sr1,sr1, cf1,cf1,
                                           iv1,iv1, b3, af,af, N, BPA3);
    }
  }

  // similarity: min/max pass -> slot reduce -> histogram pass
  sim_k<false><<<NT2*NT2, 256, 0, stream>>>(af1, af2, mmslot, mm, ghist);
  mmred_k<<<1, 64, 0, stream>>>(ws);
  sim_k<true ><<<NT2*NT2, 256, 0, stream>>>(af1, af2, mmslot, mm, ghist);

  // attention pooling (both graphs per launch)
  colsum_k<<<128, 256, 0, stream>>>(af1, af2, ws+S_CSUM1, N);
  gc_k<<<1, 64, 0, stream>>>(ws, att_w, ws);
  attpool_k<<<160, 256, 0, stream>>>(af1, af2, ws, N);

  // tensor-network scores
  bbuild_k<<<3, 512, 0, stream>>>(ws, tn_w, tn_wb, tn_bias);
  tnmean_k<<<160, 256, 0, stream>>>(af1, af2, ws, N);

  // head
  final_k<<<1, 64, 0, stream>>>(ws, ghist, fc1_w, fc1_b, fc2_w, fc2_b, out);
}

// Round 6
// 811.829 us; speedup vs baseline: 4.1637x; 1.0568x over previous
//
#include <hip/hip_runtime.h>
#include <math.h>

#define N_NODES 10000
#define E_      320000
#define NT2     79                  // ceil(10000/128)
#define NPAD2   (NT2*128)           // 10112
#define PADK    36                  // sim tile row stride (floats)

// ---- small workspace area (float offsets), same in both layouts ----
#define S_CSUM1 0
#define S_CSUM2 32
#define S_P1    128
#define S_P2    160
#define S_S1ACC 192
#define S_S2ACC 208
#define S_HIST  1296              // 64*16 u32 -> [1296,2320)
#define ZERO_SMALL 2320
#define S_MMSLOT 2320             // 128 u32 (min[64], max[64])
#define S_MM     2448             // 2 u32
#define SMALL_END 2560

#define WS_BIG_END 7149736ull     // floats (~28.6 MB)

__device__ __forceinline__ unsigned f2ord(float f){
  unsigned u = __float_as_uint(f);
  return (u & 0x80000000u) ? ~u : (u | 0x80000000u);
}
__device__ __forceinline__ float ord2f(unsigned u){
  return (u & 0x80000000u) ? __uint_as_float(u & 0x7FFFFFFFu) : __uint_as_float(~u);
}

__global__ void init_k(float* ws, int* cnA, int* cnB, float* af1, float* af2){
  int i = blockIdx.x*blockDim.x + threadIdx.x;   // grid covers [0,10000)
  if(i < ZERO_SMALL) ws[i] = 0.f;
  if(i < 128){
    unsigned* sl = (unsigned*)(ws + S_MMSLOT);
    sl[i] = (i < 64) ? 0xFFFFFFFFu : 0u;
  }
  if(i < 2){
    unsigned* mm = (unsigned*)(ws + S_MM);
    mm[i] = (i==0) ? 0xFFFFFFFFu : 0u;
  }
  if(i < N_NODES){ cnA[i] = 0; cnB[i] = 0; }
  if(i < (NPAD2 - N_NODES)*32){     // zero af pad rows
    af1[N_NODES*32 + i] = 0.f;
    af2[N_NODES*32 + i] = 0.f;
  }
}

__global__ void zero_k(int* p, int n){
  int i = blockIdx.x*blockDim.x + threadIdx.x;
  if(i < n) p[i] = 0;
}

// LDS-privatized degree histogram: 16 blocks per graph, no hot global atomics
__global__ __launch_bounds__(256) void deg2_k(const int* __restrict__ dstA,
                                              const int* __restrict__ dstB,
                                              int* __restrict__ cntA,
                                              int* __restrict__ cntB, int E){
  __shared__ int h[N_NODES];
  for(int i=threadIdx.x;i<N_NODES;i+=256) h[i]=0;
  __syncthreads();
  int g = blockIdx.x >> 4;
  int chunk = blockIdx.x & 15;
  const int* dst = g ? dstB : dstA;
  int* cnt       = g ? cntB : cntA;
  int per = (E + 15)/16;
  int s = chunk*per, e = min(s+per, E);
  for(int i=s+threadIdx.x; i<e; i+=256) atomicAdd(&h[dst[i]], 1);
  __syncthreads();
  for(int i=threadIdx.x;i<N_NODES;i+=256){
    int v = h[i];
    if(v) atomicAdd(&cnt[i], v);
  }
}

// block b scans graph b: exclusive scan of int counts -> off[n+1], cur[n]; dinv/inv
__global__ void scan_k(const int* cn0, float* dv0, float* iv0, int* of0, int* cu0,
                       const int* cn1, float* dv1, float* iv1, int* of1, int* cu1, int n){
  const int* cnt = blockIdx.x ? cn1 : cn0;
  float* dinv    = blockIdx.x ? dv1 : dv0;
  float* inv     = blockIdx.x ? iv1 : iv0;
  int* off       = blockIdx.x ? of1 : of0;
  int* cur       = blockIdx.x ? cu1 : cu0;
  __shared__ int part[256];
  int t = threadIdx.x;
  int chunk = (n + 255)/256;
  int start = t*chunk, end = min(start+chunk, n);
  int s = 0;
  for(int i=start;i<end;i++) s += cnt[i];
  part[t] = s; __syncthreads();
  if(t==0){
    int run = 0;
    for(int i=0;i<256;i++){ int v=part[i]; part[i]=run; run+=v; }
  }
  __syncthreads();
  int run = part[t];
  for(int i=start;i<end;i++){
    off[i]=run; cur[i]=run; run += cnt[i];
  }
  if(end==n) off[n]=run;
  for(int i=start;i<end;i++){
    float d = (float)cnt[i] + 1.0f;
    dinv[i] = 1.0f/sqrtf(d);
    inv[i]  = 1.0f/d;
  }
}

// bucket edges into CSR, storing src AND precomputed coef = dinv[s]*dinv[d]
__global__ void bucket_k(const int* __restrict__ eA, const int* __restrict__ eB,
                         int* curA, int* curB,
                         const float* __restrict__ dvA, const float* __restrict__ dvB,
                         int* __restrict__ srA, int* __restrict__ srB,
                         float* __restrict__ cfA, float* __restrict__ cfB,
                         int E, int nTot){
  int i = blockIdx.x*blockDim.x + threadIdx.x;
  if(i >= nTot) return;
  bool b = i >= E;
  int e = b ? i-E : i;
  const int* ei = b ? eB : eA;
  int* cur = b ? curB : curA;
  const float* dv = b ? dvB : dvA;
  int* ss = b ? srB : srA;
  float* cc = b ? cfB : cfA;
  int s = ei[e], d = ei[E+e];
  int pos = atomicAdd(&cur[d], 1);
  ss[pos] = s;
  cc[pos] = dv[s]*dv[d];
}

// C[n,FOUT] = act(A[n,FIN]) @ W[FIN,FOUT], 4 outputs/thread, dual-graph
template<int FIN, int FOUT, bool RELU>
__global__ __launch_bounds__(256) void gemm_k(const float* __restrict__ A0,
                                              const float* __restrict__ A1,
                                              const float* __restrict__ W,
                                              float* __restrict__ C0,
                                              float* __restrict__ C1,
                                              int n, int bpg){
  constexpr int KC  = (FIN > 64) ? 64 : FIN;
  constexpr int TPR = FOUT/4;
  constexpr int ROWS = 256/TPR;
  __shared__ float4 Ws[KC*TPR];
  bool gsel = blockIdx.x >= bpg;
  int blk = gsel ? blockIdx.x - bpg : blockIdx.x;
  const float* A = gsel ? A1 : A0;
  float* C       = gsel ? C1 : C0;
  int row = blk*ROWS + (int)threadIdx.x/TPR;
  int c4  = threadIdx.x % TPR;
  float4 acc = {0.f,0.f,0.f,0.f};
  const float4* W4 = (const float4*)W;
  for(int kc=0; kc<FIN; kc+=KC){
    __syncthreads();
    for(int t=threadIdx.x; t<KC*TPR; t+=256) Ws[t] = W4[(size_t)kc*TPR + t];
    __syncthreads();
    if(row < n){
      const float* a = A + (size_t)row*FIN + kc;
      #pragma unroll
      for(int k=0;k<KC;k++){
        float v = a[k];
        if(RELU) v = fmaxf(v, 0.f);
        float4 w = Ws[k*TPR + c4];
        acc.x = fmaf(v, w.x, acc.x);
        acc.y = fmaf(v, w.y, acc.y);
        acc.z = fmaf(v, w.z, acc.z);
        acc.w = fmaf(v, w.w, acc.w);
      }
    }
  }
  if(row < n) ((float4*)C)[(size_t)row*TPR + c4] = acc;
}

// fused gather-aggregation: out[d] = b + h[d]*inv[d] + sum coefs[p]*h[srcs[p]]
template<int F>
__global__ __launch_bounds__(256) void aggr_k(const float* __restrict__ h0,
                                              const float* __restrict__ h1,
                                              const int* __restrict__ of0,
                                              const int* __restrict__ of1,
                                              const int* __restrict__ sr0,
                                              const int* __restrict__ sr1,
                                              const float* __restrict__ cf0,
                                              const float* __restrict__ cf1,
                                              const float* __restrict__ iv0,
                                              const float* __restrict__ iv1,
                                              const float* __restrict__ bias,
                                              float* __restrict__ o0,
                                              float* __restrict__ o1,
                                              int n, int bpg){
  constexpr int G = F/4;
  constexpr int NPB = 256/G;
  bool gsel = blockIdx.x >= bpg;
  int blk = gsel ? blockIdx.x - bpg : blockIdx.x;
  const float* h = gsel ? h1 : h0;
  const int* off = gsel ? of1 : of0;
  const int* srcs = gsel ? sr1 : sr0;
  const float* cf = gsel ? cf1 : cf0;
  const float* inv = gsel ? iv1 : iv0;
  float* out = gsel ? o1 : o0;
  int node = blk*NPB + (int)threadIdx.x/G;
  int g = threadIdx.x % G;
  if(node >= n) return;
  const float4* h4 = (const float4*)h;
  float4 b4 = ((const float4*)bias)[g];
  float4 hv = h4[(size_t)node*G + g];
  float iv = inv[node];
  float4 acc;
  acc.x = fmaf(hv.x, iv, b4.x);
  acc.y = fmaf(hv.y, iv, b4.y);
  acc.z = fmaf(hv.z, iv, b4.z);
  acc.w = fmaf(hv.w, iv, b4.w);
  int p = off[node], p1 = off[node+1];
  for(; p+4<=p1; p+=4){
    int s0=srcs[p], s1=srcs[p+1], s2=srcs[p+2], s3=srcs[p+3];
    float c0=cf[p], c1=cf[p+1], c2=cf[p+2], c3=cf[p+3];
    float4 v0=h4[(size_t)s0*G+g], v1=h4[(size_t)s1*G+g];
    float4 v2=h4[(size_t)s2*G+g], v3=h4[(size_t)s3*G+g];
    acc.x=fmaf(c0,v0.x,acc.x); acc.y=fmaf(c0,v0.y,acc.y); acc.z=fmaf(c0,v0.z,acc.z); acc.w=fmaf(c0,v0.w,acc.w);
    acc.x=fmaf(c1,v1.x,acc.x); acc.y=fmaf(c1,v1.y,acc.y); acc.z=fmaf(c1,v1.z,acc.z); acc.w=fmaf(c1,v1.w,acc.w);
    acc.x=fmaf(c2,v2.x,acc.x); acc.y=fmaf(c2,v2.y,acc.y); acc.z=fmaf(c2,v2.z,acc.z); acc.w=fmaf(c2,v2.w,acc.w);
    acc.x=fmaf(c3,v3.x,acc.x); acc.y=fmaf(c3,v3.y,acc.y); acc.z=fmaf(c3,v3.z,acc.z); acc.w=fmaf(c3,v3.w,acc.w);
  }
  for(; p<p1; ++p){
    int s = srcs[p];
    float c = cf[p];
    float4 v = h4[(size_t)s*G + g];
    acc.x=fmaf(c,v.x,acc.x); acc.y=fmaf(c,v.y,acc.y);
    acc.z=fmaf(c,v.z,acc.z); acc.w=fmaf(c,v.w,acc.w);
  }
  ((float4*)out)[(size_t)node*G + g] = acc;
}

// 128x128 tile, 8x8 microtile, stride-36 tiles (round-4 body; lh aliased on ta)
template<bool HIST>
__global__ __launch_bounds__(256,4) void sim_k(const float* __restrict__ af1,
                                               const float* __restrict__ af2,
                                               unsigned* __restrict__ mmslot,
                                               const unsigned* __restrict__ mm,
                                               unsigned* __restrict__ ghist){
  __shared__ __align__(16) float ta[128*PADK];
  __shared__ __align__(16) float tb[128*PADK];
  unsigned* lh = (unsigned*)ta;      // reused AFTER compute (behind barrier)
  int bx = blockIdx.x % NT2, by = blockIdx.x / NT2;
  int i0 = by*128, j0 = bx*128;
  {
    int row  = threadIdx.x & 127;
    int half = (threadIdx.x >> 7) * 4;
    const float4* A4 = (const float4*)(af1 + (size_t)(i0+row)*32);
    const float4* B4 = (const float4*)(af2 + (size_t)(j0+row)*32);
    float4* tar = (float4*)(ta + row*PADK);
    float4* tbr = (float4*)(tb + row*PADK);
    #pragma unroll
    for(int j=0;j<4;j++){ tar[half+j] = A4[half+j]; tbr[half+j] = B4[half+j]; }
  }
  __syncthreads();
  int tx = threadIdx.x & 15, ty = threadIdx.x >> 4;
  float acc[8][8];
  #pragma unroll
  for(int r=0;r<8;r++)
    #pragma unroll
    for(int c=0;c<8;c++) acc[r][c]=0.f;
  #pragma unroll 1
  for(int kk=0; kk<32; kk+=4){
    float4 a[8], b[8];
    #pragma unroll
    for(int r=0;r<8;r++) a[r] = *(const float4*)(ta + (ty+16*r)*PADK + kk);
    #pragma unroll
    for(int c=0;c<8;c++) b[c] = *(const float4*)(tb + (tx+16*c)*PADK + kk);
    #pragma unroll
    for(int r=0;r<8;r++){
      #pragma unroll
      for(int c=0;c<8;c++){
        float v = acc[r][c];
        v = fmaf(a[r].x, b[c].x, v);
        v = fmaf(a[r].y, b[c].y, v);
        v = fmaf(a[r].z, b[c].z, v);
        v = fmaf(a[r].w, b[c].w, v);
        acc[r][c] = v;
      }
    }
  }
  bool full = (i0+128 <= N_NODES) && (j0+128 <= N_NODES);
  if(!HIST){
    float m = INFINITY, M = -INFINITY;
    if(full){
      #pragma unroll
      for(int r=0;r<8;r++)
        #pragma unroll
        for(int c=0;c<8;c++){ float v=acc[r][c]; m=fminf(m,v); M=fmaxf(M,v); }
    } else {
      for(int r=0;r<8;r++){
        if(i0+ty+16*r >= N_NODES) continue;
        for(int c=0;c<8;c++){
          if(j0+tx+16*c >= N_NODES) continue;
          float v=acc[r][c]; m=fminf(m,v); M=fmaxf(M,v);
        }
      }
    }
    #pragma unroll
    for(int off=32; off; off>>=1){
      m = fminf(m, __shfl_down(m, off, 64));
      M = fmaxf(M, __shfl_down(M, off, 64));
    }
    if((threadIdx.x & 63)==0){
      int slot = (blockIdx.x*4 + (threadIdx.x>>6)) & 63;
      atomicMin(&mmslot[slot],    f2ord(m));
      atomicMax(&mmslot[64+slot], f2ord(M));
    }
  } else {
    float lo = ord2f(mm[0]);
    float hi = ord2f(mm[1]);
    float denom = (hi-lo) + 1e-12f;
    __syncthreads();                 // everyone done reading ta
    for(int t=threadIdx.x; t<64*17; t+=256) lh[t]=0u;
    __syncthreads();
    unsigned base = (threadIdx.x & 63)*17;
    if(full){
      #pragma unroll
      for(int r=0;r<8;r++)
        #pragma unroll
        for(int c=0;c<8;c++){
          int idx = (int)((acc[r][c]-lo)/denom*16.0f);   // exact reference op order
          idx = idx<0 ? 0 : (idx>15 ? 15 : idx);
          atomicAdd(&lh[base+idx], 1u);
        }
    } else {
      for(int r=0;r<8;r++){
        if(i0+ty+16*r >= N_NODES) continue;
        for(int c=0;c<8;c++){
          if(j0+tx+16*c >= N_NODES) continue;
          int idx = (int)((acc[r][c]-lo)/denom*16.0f);
          idx = idx<0 ? 0 : (idx>15 ? 15 : idx);
          atomicAdd(&lh[base+idx], 1u);
        }
      }
    }
    __syncthreads();
    if(threadIdx.x<16){
      unsigned s=0;
      for(int w=0;w<64;w++) s += lh[w*17+threadIdx.x];
      atomicAdd(&ghist[(blockIdx.x & 63)*16 + threadIdx.x], s);
    }
  }
}

__global__ void mmred_k(float* ws){
  unsigned* sl = (unsigned*)(ws + S_MMSLOT);
  unsigned* mm = (unsigned*)(ws + S_MM);
  int t = threadIdx.x;   // 64 threads
  unsigned mn = sl[t], mx = sl[64+t];
  #pragma unroll
  for(int off=32; off; off>>=1){
    mn = min(mn, (unsigned)__shfl_down((int)mn, off, 64));
    mx = max(mx, (unsigned)__shfl_down((int)mx, off, 64));
  }
  if(t==0){ mm[0]=mn; mm[1]=mx; }
}

// blocks [0,64) -> graph1, [64,128) -> graph2
__global__ void colsum_k(const float* __restrict__ af1, const float* __restrict__ af2,
                         float* __restrict__ csum, int n){
  bool g2 = blockIdx.x >= 64;
  const float* af = g2 ? af2 : af1;
  float* cs = csum + (g2 ? S_CSUM2 - S_CSUM1 : 0);
  int blk = blockIdx.x & 63;
  int f = threadIdx.x % 32;
  int rg = threadIdx.x / 32;
  float acc = 0.f;
  for(int node = blk*8 + rg; node < n; node += 64*8)
    acc += af[(size_t)node*32 + f];
  __shared__ float s[256];
  s[threadIdx.x]=acc; __syncthreads();
  if(threadIdx.x<32){
    float v=0.f;
    for(int r=0;r<8;r++) v += s[r*32+threadIdx.x];
    atomicAdd(&cs[threadIdx.x], v);
  }
}

// blocks [0,80) -> graph1, [80,160) -> graph2; gc computed inline from csum
__global__ __launch_bounds__(256) void attpool_k(const float* __restrict__ af1,
                                                 const float* __restrict__ af2,
                                                 const float* __restrict__ att_w,
                                                 float* __restrict__ wsmall, int n){
  bool g2 = blockIdx.x >= 80;
  const float* af   = g2 ? af2 : af1;
  const float* csum = wsmall + (g2 ? S_CSUM2 : S_CSUM1);
  float* p          = wsmall + (g2 ? S_P2  : S_P1);
  int blk = g2 ? blockIdx.x-80 : blockIdx.x;
  __shared__ float sgc[32];
  if(threadIdx.x<32){
    int j = threadIdx.x;
    float acc = 0.f;
    for(int f=0;f<32;f++) acc += csum[f]*att_w[f*32+j];
    sgc[j] = tanhf(acc * (1.0f/N_NODES));
  }
  __syncthreads();
  float pacc[32];
  #pragma unroll
  for(int f=0;f<32;f++) pacc[f]=0.f;
  for(int node = blk*256 + threadIdx.x; node < n; node += 80*256){
    const float* row = af + (size_t)node*32;
    float d = 0.f;
    #pragma unroll
    for(int f=0;f<32;f++) d += row[f]*sgc[f];
    float sig = 1.0f/(1.0f+expf(-d));
    #pragma unroll
    for(int f=0;f<32;f++) pacc[f] += row[f]*sig;
  }
  #pragma unroll
  for(int f=0;f<32;f++){
    float v = pacc[f];
    for(int off=32; off; off>>=1) v += __shfl_down(v, off, 64);
    if((threadIdx.x & 63)==0) atomicAdd(&p[f], v);
  }
}

// blocks [0,80) -> af1 w/ B from p2 -> S1ACC, [80,160) -> af2 w/ B from p1 -> S2ACC
// B, c built inline (identical math to old bbuild_k)
__global__ __launch_bounds__(256) void tnmean_k(const float* __restrict__ af1,
                                                const float* __restrict__ af2,
                                                const float* __restrict__ tn_w,
                                                const float* __restrict__ tn_wb,
                                                const float* __restrict__ tn_bias,
                                                float* __restrict__ wsmall, int n){
  bool g2 = blockIdx.x >= 80;
  const float* X  = g2 ? af2 : af1;
  const float* pv = wsmall + (g2 ? S_P1 : S_P2);
  float* acc_out  = wsmall + (g2 ? S_S2ACC : S_S1ACC);
  int blk = g2 ? blockIdx.x-80 : blockIdx.x;
  __shared__ float sB[512];
  __shared__ float sc[16];
  for(int e=threadIdx.x; e<512; e+=256){
    int g = e/16, k = e%16;
    float acc = 0.f;
    for(int f=0;f<32;f++) acc += tn_w[(g*32+f)*16+k]*pv[f];
    sB[e] = acc + tn_wb[k*64+g];
  }
  if(threadIdx.x<16){
    int k = threadIdx.x;
    float acc = 0.f;
    for(int f=0;f<32;f++) acc += tn_wb[k*64+32+f]*pv[f];
    sc[k] = acc + tn_bias[k];
  }
  __syncthreads();
  float a[16];
  #pragma unroll
  for(int k=0;k<16;k++) a[k]=0.f;
  for(int node = blk*256 + threadIdx.x; node < n; node += 80*256){
    const float* row = X + (size_t)node*32;
    float rv[32];
    #pragma unroll
    for(int g=0;g<32;g++) rv[g]=row[g];
    #pragma unroll
    for(int k=0;k<16;k++){
      float y = sc[k];
      #pragma unroll
      for(int g=0;g<32;g++) y += rv[g]*sB[g*16+k];
      a[k] += fmaxf(y, 0.f);
    }
  }
  #pragma unroll
  for(int k=0;k<16;k++){
    float v = a[k];
    for(int off=32; off; off>>=1) v += __shfl_down(v, off, 64);
    if((threadIdx.x & 63)==0) atomicAdd(&acc_out[k], v);
  }
}

// parallel head: 64 threads, 1 block; s0 computed inline
__global__ void final_k(const float* __restrict__ ws, const unsigned* __restrict__ ghist,
                        const float* __restrict__ tn_w, const float* __restrict__ tn_wb,
                        const float* __restrict__ tn_bias,
                        const float* __restrict__ fc1_w, const float* __restrict__ fc1_b,
                        const float* __restrict__ fc2_w, const float* __restrict__ fc2_b,
                        float* __restrict__ out){
  __shared__ float sc[64];
  __shared__ float hraw[16];
  __shared__ float sh[16];
  int t = threadIdx.x;
  const float invN = 1.0f/N_NODES;
  if(t<16){
    const float* p1 = ws + S_P1;
    const float* p2 = ws + S_P2;
    float s = 0.f;
    for(int f1=0;f1<32;f1++){
      float a = p1[f1];
      for(int f2=0;f2<32;f2++) s += a*tn_w[(f1*32+f2)*16+t]*p2[f2];
    }
    float blk = 0.f;
    for(int f=0;f<32;f++) blk += tn_wb[t*64+f]*p1[f] + tn_wb[t*64+32+f]*p2[f];
    sc[t] = fmaxf(s + blk + tn_bias[t], 0.f);
  }
  else if(t<32) sc[t] = ws[S_S1ACC+(t-16)]*invN;
  else if(t<48) sc[t] = ws[S_S2ACC+(t-32)]*invN;
  int bin = t & 15, grp = t >> 4;
  unsigned c = 0;
  for(int s=grp; s<64; s+=4) c += ghist[s*16+bin];
  c += (unsigned)__shfl_down((int)c, 32, 64);
  c += (unsigned)__shfl_down((int)c, 16, 64);
  if(t<16){
    float v = (float)c;
    if(v > 16777216.0f) v = 16777216.0f;   // fp32 +1.0 saturation emulation
    hraw[t] = v;
  }
  __syncthreads();
  if(t<16){
    float tot = 0.f;
    for(int b=0;b<16;b++) tot += hraw[b];   // same serial order as reference
    sc[48+t] = hraw[t]/tot;
  }
  __syncthreads();
  if(t<16){
    float a = fc1_b[t];
    for(int i=0;i<64;i++) a += sc[i]*fc1_w[i*16+t];
    sh[t] = fmaxf(a, 0.f);
  }
  __syncthreads();
  if(t==0){
    float o = fc2_b[0];
    for(int j=0;j<16;j++) o += sh[j]*fc2_w[j];
    out[0] = 1.0f/(1.0f+expf(-o));
  }
}

extern "C" void kernel_launch(void* const* d_in, const int* in_sizes, int n_in,
                              void* d_out, int out_size, void* d_ws, size_t ws_size,
                              hipStream_t stream){
  const float* x1      = (const float*)d_in[0];
  const float* x2      = (const float*)d_in[1];
  const int*   ei1     = (const int*)d_in[2];
  const int*   ei2     = (const int*)d_in[3];
  const float* W1      = (const float*)d_in[4];
  const float* b1      = (const float*)d_in[5];
  const float* W2      = (const float*)d_in[6];
  const float* b2      = (const float*)d_in[7];
  const float* W3      = (const float*)d_in[8];
  const float* b3      = (const float*)d_in[9];
  const float* att_w   = (const float*)d_in[10];
  const float* tn_w    = (const float*)d_in[11];
  const float* tn_wb   = (const float*)d_in[12];
  const float* tn_bias = (const float*)d_in[13];
  const float* fc1_w   = (const float*)d_in[14];
  const float* fc1_b   = (const float*)d_in[15];
  const float* fc2_w   = (const float*)d_in[16];
  const float* fc2_b   = (const float*)d_in[17];

  float* ws = (float*)d_ws;
  float* out = (float*)d_out;
  const int N = N_NODES, E = E_;

  bool big = ws_size >= WS_BIG_END*sizeof(float);

  size_t oCN1,oCN2,oDV1,oDV2,oIV1,oIV2,oOF1,oOF2,oCU1,oCU2,oSR1,oSR2,
         oCF1,oCF2,oBH1,oBH2,oBO1,oBO2,oAF1,oAF2;
  if(big){
    oCN1=2560;    oCN2=12560;   oDV1=22560;   oDV2=32560;
    oIV1=42560;   oIV2=52560;   oOF1=62560;   oOF2=72564;
    oCU1=82568;   oCU2=92568;   oSR1=102568;  oSR2=422568;
    oCF1=742568;  oCF2=1062568; oBH1=1382568; oBH2=2662568;
    oBO1=3942568; oBO2=5222568; oAF1=6502568; oAF2=6826152;
  } else {
    oCN1=2560;    oCN2=oCN1;    oDV1=12560;   oDV2=oDV1;
    oIV1=22560;   oIV2=oIV1;    oOF1=32560;   oOF2=oOF1;
    oCU1=42564;   oCU2=oCU1;    oSR1=52564;   oSR2=oSR1;
    oCF1=372564;  oCF2=oCF1;    oBH1=692564;  oBH2=oBH1;
    oBO1=1972564; oBO2=oBO1;    oAF1=3252564; oAF2=3576148;
  }
  int* cn1=(int*)(ws+oCN1); int* cn2=(int*)(ws+oCN2);
  float* dv1=ws+oDV1; float* dv2=ws+oDV2;
  float* iv1=ws+oIV1; float* iv2=ws+oIV2;
  int* of1=(int*)(ws+oOF1); int* of2=(int*)(ws+oOF2);
  int* cu1=(int*)(ws+oCU1); int* cu2=(int*)(ws+oCU2);
  int* sr1=(int*)(ws+oSR1); int* sr2=(int*)(ws+oSR2);
  float* cf1=ws+oCF1; float* cf2=ws+oCF2;
  float* bh1=ws+oBH1; float* bh2=ws+oBH2;
  float* bo1=ws+oBO1; float* bo2=ws+oBO2;
  float* af1=ws+oAF1; float* af2=ws+oAF2;

  unsigned* mmslot = (unsigned*)(ws + S_MMSLOT);
  unsigned* mm     = (unsigned*)(ws + S_MM);
  unsigned* ghist  = (unsigned*)(ws + S_HIST);

  const int BPG1 = (N+7)/8,  BPA1 = (N+1)/2;    // gemm/aggr F=128
  const int BPG2 = (N+15)/16, BPA2 = (N+3)/4;   // F=64
  const int BPG3 = (N+31)/32, BPA3 = (N+7)/8;   // F=32

  init_k<<<(N+255)/256, 256, 0, stream>>>(ws, cn1, cn2, af1, af2);

  if(big){
    deg2_k<<<32, 256, 0, stream>>>(ei1+E, ei2+E, cn1, cn2, E);
    scan_k<<<2, 256, 0, stream>>>(cn1, dv1, iv1, of1, cu1,
                                  cn2, dv2, iv2, of2, cu2, N);
    bucket_k<<<(2*E+255)/256, 256, 0, stream>>>(ei1, ei2, cu1, cu2, dv1, dv2,
                                                sr1, sr2, cf1, cf2, E, 2*E);
    gemm_k<128,128,false><<<2*BPG1, 256, 0, stream>>>(x1, x2, W1, bh1, bh2, N, BPG1);
    aggr_k<128><<<2*BPA1, 256, 0, stream>>>(bh1,bh2, of1,of2, sr1,sr2, cf1,cf2,
                                            iv1,iv2, b1, bo1,bo2, N, BPA1);
    gemm_k<128,64,true><<<2*BPG2, 256, 0, stream>>>(bo1, bo2, W2, bh1, bh2, N, BPG2);
    aggr_k<64><<<2*BPA2, 256, 0, stream>>>(bh1,bh2, of1,of2, sr1,sr2, cf1,cf2,
                                           iv1,iv2, b2, bo1,bo2, N, BPA2);
    gemm_k<64,32,true><<<2*BPG3, 256, 0, stream>>>(bo1, bo2, W3, bh1, bh2, N, BPG3);
    aggr_k<32><<<2*BPA3, 256, 0, stream>>>(bh1,bh2, of1,of2, sr1,sr2, cf1,cf2,
                                           iv1,iv2, b3, af1,af2, N, BPA3);
  } else {
    for(int g=0; g<2; g++){
      const float* x = g ? x2 : x1;
      const int* ei  = g ? ei2 : ei1;
      float* af      = g ? af2 : af1;
      if(g) zero_k<<<(N+255)/256, 256, 0, stream>>>(cn1, N);
      deg2_k<<<16, 256, 0, stream>>>(ei+E, ei+E, cn1, cn1, E);
      scan_k<<<1, 256, 0, stream>>>(cn1, dv1, iv1, of1, cu1,
                                    cn1, dv1, iv1, of1, cu1, N);
      bucket_k<<<(E+255)/256, 256, 0, stream>>>(ei, ei, cu1, cu1, dv1, dv1,
                                                sr1, sr1, cf1, cf1, E, E);
      gemm_k<128,128,false><<<BPG1, 256, 0, stream>>>(x, x, W1, bh1, bh1, N, BPG1);
      aggr_k<128><<<BPA1, 256, 0, stream>>>(bh1,bh1, of1,of1, sr1,sr1, cf1,cf1,
                                            iv1,iv1, b1, bo1,bo1, N, BPA1);
      gemm_k<128,64,true><<<BPG2, 256, 0, stream>>>(bo1, bo1, W2, bh1, bh1, N, BPG2);
      aggr_k<64><<<BPA2, 256, 0, stream>>>(bh1,bh1, of1,of1, sr1,sr1, cf1,cf1,
                                           iv1,iv1, b2, bo1,bo1, N, BPA2);
      gemm_k<64,32,true><<<BPG3, 256, 0, stream>>>(bo1, bo1, W3, bh1, bh1, N, BPG3);
      aggr_k<32><<<BPA3, 256, 0, stream>>>(bh1,bh1, of1,of1, sr1,sr1, cf1,cf1,
                                           iv1,iv1, b3, af,af, N, BPA3);
    }
  }

  // similarity: min/max pass -> slot reduce -> histogram pass
  sim_k<false><<<NT2*NT2, 256, 0, stream>>>(af1, af2, mmslot, mm, ghist);
  mmred_k<<<1, 64, 0, stream>>>(ws);
  sim_k<true ><<<NT2*NT2, 256, 0, stream>>>(af1, af2, mmslot, mm, ghist);

  // attention pooling (gc inline)
  colsum_k<<<128, 256, 0, stream>>>(af1, af2, ws+S_CSUM1, N);
  attpool_k<<<160, 256, 0, stream>>>(af1, af2, att_w, ws, N);

  // tensor-network scores (B/c inline)
  tnmean_k<<<160, 256, 0, stream>>>(af1, af2, tn_w, tn_wb, tn_bias, ws, N);

  // head (s0 inline)
  final_k<<<1, 64, 0, stream>>>(ws, ghist, tn_w, tn_wb, tn_bias,
                                fc1_w, fc1_b, fc2_w, fc2_b, out);
}